// Round 2
// baseline (407.003 us; speedup 1.0000x reference)
//
#include <hip/hip_runtime.h>
#include <cstdint>

#define D_MODEL 1024
#define NHEAD 16
#define HEAD_DIM 64
#define LSEQ 2048
#define BATCH 4
#define MROWS (BATCH * LSEQ)  // 8192

typedef __bf16 bf16x8 __attribute__((ext_vector_type(8)));
typedef float f32x4 __attribute__((ext_vector_type(4)));

// fp32 -> bf16 RNE
__device__ __forceinline__ unsigned short f2bf(float f) {
    unsigned b = __builtin_bit_cast(unsigned, f);
    b += 0x7FFFu + ((b >> 16) & 1u);
    return (unsigned short)(b >> 16);
}

// async global->LDS, 16B per lane; lds must be wave-uniform base (lane*16 added by HW)
__device__ __forceinline__ void load16_lds(const void* g, void* lds) {
    __builtin_amdgcn_global_load_lds(
        (const __attribute__((address_space(1))) void*)(uintptr_t)g,
        (__attribute__((address_space(3))) void*)(unsigned)(uintptr_t)lds,
        16, 0, 0);
}

// Swizzled ushort index into a [rows][64]-ushort (128B-row) LDS tile.
// XOR of the 16B-chunk index with (row&7): spreads the 16-lane column reads
// across all banks (2 lanes/bank = free per m136). Same involution is applied
// to the global SOURCE during global_load_lds staging (rule #21).
__device__ __forceinline__ int lidx(int row, int col /*ushort units*/) {
    return row * 64 + (col ^ ((row & 7) << 3));
}

// ---------------------------------------------------------------------------
__global__ __launch_bounds__(256) void cvt_bf16(const float* __restrict__ in,
                                                unsigned short* __restrict__ out,
                                                int n4) {
    int i = blockIdx.x * 256 + threadIdx.x;
    if (i >= n4) return;
    float4 v = ((const float4*)in)[i];
    ushort4 o;
    o.x = f2bf(v.x); o.y = f2bf(v.y); o.z = f2bf(v.z); o.w = f2bf(v.w);
    ((ushort4*)out)[i] = o;
}

// ---------------------------------------------------------------------------
// QKV projection: C = X @ W^T + b, 128x128 tile, BK=64, 4 waves, MFMA 16x16x32.
// z = 0/1/2 -> Q/K/V.  Q,K: fused per-head L2norm * scale (Q also * hd^-0.5),
// layout [B,H,L,64].  V: written transposed [B,H,64,L].
// ---------------------------------------------------------------------------
__global__ __launch_bounds__(256) void qkv_mfma(
    const unsigned short* __restrict__ xb,
    const unsigned short* __restrict__ Wqb, const float* __restrict__ bq,
    const unsigned short* __restrict__ Wkb, const float* __restrict__ bk,
    const unsigned short* __restrict__ Wvb, const float* __restrict__ bv,
    const float* __restrict__ scale,
    unsigned short* __restrict__ Qo, unsigned short* __restrict__ Ko,
    unsigned short* __restrict__ Vt)
{
    __shared__ __align__(16) unsigned short Als[128 * 64];
    __shared__ __align__(16) unsigned short Bls[128 * 64];

    const int z = blockIdx.z;
    const unsigned short* Wb = (z == 0) ? Wqb : (z == 1) ? Wkb : Wvb;
    const float* bias        = (z == 0) ? bq  : (z == 1) ? bk  : bv;

    const int tid = threadIdx.x;
    const int w = tid >> 6, lane = tid & 63;
    const int wm = w >> 1, wn = w & 1;
    const int fr = lane & 15, fq = lane >> 4;
    const int i0 = blockIdx.x * 128, j0 = blockIdx.y * 128;

    // staging: row-within-8 = lane>>3, source chunk pre-swizzled
    const int sr = lane >> 3;
    const int scs = ((lane & 7) ^ (lane >> 3)) * 8;  // inverse-swizzled col (ushorts)

    f32x4 acc[4][4] = {};

    for (int kt = 0; kt < D_MODEL / 64; ++kt) {
        const int k0 = kt * 64;
        __syncthreads();
#pragma unroll
        for (int t = 0; t < 4; ++t) {
            const int row = w * 32 + t * 8;
            load16_lds(&xb[(size_t)(i0 + row + sr) * D_MODEL + k0 + scs], &Als[row * 64]);
            load16_lds(&Wb[(size_t)(j0 + row + sr) * D_MODEL + k0 + scs], &Bls[row * 64]);
        }
        __syncthreads();
#pragma unroll
        for (int kh = 0; kh < 2; ++kh) {
            bf16x8 af[4], bfr[4];
#pragma unroll
            for (int mf = 0; mf < 4; ++mf)
                af[mf] = *(const bf16x8*)&Als[lidx(wm * 64 + mf * 16 + fr, kh * 32 + fq * 8)];
#pragma unroll
            for (int nf = 0; nf < 4; ++nf)
                bfr[nf] = *(const bf16x8*)&Bls[lidx(wn * 64 + nf * 16 + fr, kh * 32 + fq * 8)];
#pragma unroll
            for (int mf = 0; mf < 4; ++mf)
#pragma unroll
                for (int nf = 0; nf < 4; ++nf)
                    acc[mf][nf] = __builtin_amdgcn_mfma_f32_16x16x32_bf16(
                        af[mf], bfr[nf], acc[mf][nf], 0, 0, 0);
        }
    }

    float bb[4];
#pragma unroll
    for (int nf = 0; nf < 4; ++nf) bb[nf] = bias[j0 + wn * 64 + nf * 16 + fr];
#pragma unroll
    for (int mf = 0; mf < 4; ++mf)
#pragma unroll
        for (int nf = 0; nf < 4; ++nf)
#pragma unroll
            for (int r = 0; r < 4; ++r) acc[mf][nf][r] += bb[nf];

    const int h = (j0 >> 6) + wn;  // head index of this wave's 64-col span

    if (z < 2) {
        const float sclr = scale[0] * ((z == 0) ? 0.125f : 1.0f);  // fold hd^-0.5 into Q
        unsigned short* out = (z == 0) ? Qo : Ko;
#pragma unroll
        for (int mf = 0; mf < 4; ++mf) {
#pragma unroll
            for (int r = 0; r < 4; ++r) {
                float ss = 0.f;
#pragma unroll
                for (int nf = 0; nf < 4; ++nf) ss += acc[mf][nf][r] * acc[mf][nf][r];
                ss += __shfl_xor(ss, 1); ss += __shfl_xor(ss, 2);
                ss += __shfl_xor(ss, 4); ss += __shfl_xor(ss, 8);
                const float inv = sclr / fmaxf(sqrtf(ss), 1e-12f);
                const int i = i0 + wm * 64 + mf * 16 + fq * 4 + r;
                const int bidx = i >> 11, lrow = i & (LSEQ - 1);
                const size_t rb = (((size_t)(bidx * NHEAD + h)) * LSEQ + lrow) * HEAD_DIM;
#pragma unroll
                for (int nf = 0; nf < 4; ++nf)
                    out[rb + nf * 16 + fr] = f2bf(acc[mf][nf][r] * inv);
            }
        }
    } else {
#pragma unroll
        for (int mf = 0; mf < 4; ++mf) {
            const int i = i0 + wm * 64 + mf * 16 + fq * 4;  // r=0 row; +r contiguous
            const int bidx = i >> 11, lrow = i & (LSEQ - 1);
#pragma unroll
            for (int nf = 0; nf < 4; ++nf) {
                const int d = nf * 16 + fr;
                const size_t a = (((size_t)(bidx * NHEAD + h)) * HEAD_DIM + d) * LSEQ + lrow;
                ushort4 pk;
                pk.x = f2bf(acc[mf][nf][0]); pk.y = f2bf(acc[mf][nf][1]);
                pk.z = f2bf(acc[mf][nf][2]); pk.w = f2bf(acc[mf][nf][3]);
                *(ushort4*)&Vt[a] = pk;
            }
        }
    }
}

// ---------------------------------------------------------------------------
// Causal flash attention, bf16 MFMA.  grid=(L/64, H, B), 256 threads (4 waves),
// wave w owns 16 Q rows.  K tile + V^T tile staged in swizzled LDS; P goes
// through a per-wave swizzled LDS buffer to become MFMA A-fragments.
// Output AO[b][l][h][d] bf16 (== [B*L][1024] row-major for oproj).
// ---------------------------------------------------------------------------
__global__ __launch_bounds__(256) void attn_mfma(
    const unsigned short* __restrict__ Qb, const unsigned short* __restrict__ Kb,
    const unsigned short* __restrict__ Vt, unsigned short* __restrict__ AO)
{
    __shared__ __align__(16) unsigned short Kls[64 * 64];
    __shared__ __align__(16) unsigned short Vls[64 * 64];
    __shared__ __align__(16) unsigned short Pls[4][16 * 64];

    const int qt = blockIdx.x, h = blockIdx.y, b = blockIdx.z;
    const int tid = threadIdx.x, w = tid >> 6, lane = tid & 63;
    const int fr = lane & 15, fq = lane >> 4;

    const size_t hb = (size_t)(b * NHEAD + h);
    const unsigned short* Kg = Kb + hb * LSEQ * HEAD_DIM;
    const unsigned short* Vg = Vt + hb * HEAD_DIM * LSEQ;
    const unsigned short* Qg = Qb + hb * LSEQ * HEAD_DIM;

    bf16x8 qf[2];
    {
        const int qrow = qt * 64 + w * 16 + fr;
        qf[0] = *(const bf16x8*)&Qg[(size_t)qrow * HEAD_DIM + fq * 8];
        qf[1] = *(const bf16x8*)&Qg[(size_t)qrow * HEAD_DIM + 32 + fq * 8];
    }

    f32x4 acc_o[4] = {};
    float m_[4], ls[4];
#pragma unroll
    for (int r = 0; r < 4; ++r) { m_[r] = -INFINITY; ls[r] = 0.f; }

    const int scs = ((lane & 7) ^ (lane >> 3)) * 8;  // pre-swizzled source col

    for (int kt = 0; kt <= qt; ++kt) {
        __syncthreads();
        {
            const unsigned short* gk = Kg + (size_t)kt * 64 * HEAD_DIM;
#pragma unroll
            for (int t = 0; t < 2; ++t) {
                const int c = w * 2 + t;  // 8-row chunk 0..7
                load16_lds(gk + (size_t)(c * 8 + (lane >> 3)) * 64 + scs, &Kls[c * 8 * 64]);
                load16_lds(Vg + (size_t)(c * 8 + (lane >> 3)) * LSEQ + kt * 64 + scs,
                           &Vls[c * 8 * 64]);
            }
        }
        __syncthreads();

        // S = Q K^T (this wave's 16 rows x 64 keys)
        f32x4 s[4] = {};
#pragma unroll
        for (int nf = 0; nf < 4; ++nf) {
            bf16x8 k0 = *(const bf16x8*)&Kls[lidx(nf * 16 + fr, fq * 8)];
            bf16x8 k1 = *(const bf16x8*)&Kls[lidx(nf * 16 + fr, 32 + fq * 8)];
            s[nf] = __builtin_amdgcn_mfma_f32_16x16x32_bf16(qf[0], k0, s[nf], 0, 0, 0);
            s[nf] = __builtin_amdgcn_mfma_f32_16x16x32_bf16(qf[1], k1, s[nf], 0, 0, 0);
        }

        if (kt == qt) {  // diagonal tile: mask kv > q
#pragma unroll
            for (int nf = 0; nf < 4; ++nf)
#pragma unroll
                for (int r = 0; r < 4; ++r)
                    if (nf * 16 + fr > w * 16 + fq * 4 + r) s[nf][r] = -INFINITY;
        }

        // online softmax (row = fq*4+r within wave band; 16 lanes share a row)
        float f_[4], ps[4];
#pragma unroll
        for (int r = 0; r < 4; ++r) {
            float v = fmaxf(fmaxf(s[0][r], s[1][r]), fmaxf(s[2][r], s[3][r]));
            v = fmaxf(v, __shfl_xor(v, 1));
            v = fmaxf(v, __shfl_xor(v, 2));
            v = fmaxf(v, __shfl_xor(v, 4));
            v = fmaxf(v, __shfl_xor(v, 8));
            const float mn = fmaxf(m_[r], v);
            f_[r] = __expf(m_[r] - mn);
            m_[r] = mn;
            ps[r] = 0.f;
        }
#pragma unroll
        for (int nf = 0; nf < 4; ++nf)
#pragma unroll
            for (int r = 0; r < 4; ++r) {
                const float p = __expf(s[nf][r] - m_[r]);
                s[nf][r] = p;
                ps[r] += p;
            }
#pragma unroll
        for (int r = 0; r < 4; ++r) {
            float v = ps[r];
            v += __shfl_xor(v, 1); v += __shfl_xor(v, 2);
            v += __shfl_xor(v, 4); v += __shfl_xor(v, 8);
            ls[r] = ls[r] * f_[r] + v;
        }
#pragma unroll
        for (int nf = 0; nf < 4; ++nf)
#pragma unroll
            for (int r = 0; r < 4; ++r) acc_o[nf][r] *= f_[r];

        // P -> LDS (bf16, swizzled) ; row = fq*4+r, col = nf*16+fr
#pragma unroll
        for (int nf = 0; nf < 4; ++nf)
#pragma unroll
            for (int r = 0; r < 4; ++r)
                Pls[w][lidx(fq * 4 + r, nf * 16 + fr)] = f2bf(s[nf][r]);

        // O += P @ V   (A-frag from Pls, B-frag from V^T tile)
#pragma unroll
        for (int kf = 0; kf < 2; ++kf) {
            bf16x8 pa = *(const bf16x8*)&Pls[w][lidx(fr, kf * 32 + fq * 8)];
#pragma unroll
            for (int nf = 0; nf < 4; ++nf) {
                bf16x8 vb = *(const bf16x8*)&Vls[lidx(nf * 16 + fr, kf * 32 + fq * 8)];
                acc_o[nf] = __builtin_amdgcn_mfma_f32_16x16x32_bf16(pa, vb, acc_o[nf], 0, 0, 0);
            }
        }
    }

#pragma unroll
    for (int r = 0; r < 4; ++r) {
        const float inv = 1.f / ls[r];
        const int lq = qt * 64 + w * 16 + fq * 4 + r;
        const size_t rb = ((size_t)b * LSEQ + lq) * D_MODEL + h * HEAD_DIM;
#pragma unroll
        for (int nf = 0; nf < 4; ++nf)
            AO[rb + nf * 16 + fr] = f2bf(acc_o[nf][r] * inv);
    }
}

// ---------------------------------------------------------------------------
// Output projection: out = AO @ Wo^T + bo, fp32 output.
// ---------------------------------------------------------------------------
__global__ __launch_bounds__(256) void oproj_mfma(
    const unsigned short* __restrict__ Ab, const unsigned short* __restrict__ Wob,
    const float* __restrict__ bo, float* __restrict__ out)
{
    __shared__ __align__(16) unsigned short Als[128 * 64];
    __shared__ __align__(16) unsigned short Bls[128 * 64];

    const int tid = threadIdx.x;
    const int w = tid >> 6, lane = tid & 63;
    const int wm = w >> 1, wn = w & 1;
    const int fr = lane & 15, fq = lane >> 4;
    const int i0 = blockIdx.x * 128, j0 = blockIdx.y * 128;

    const int sr = lane >> 3;
    const int scs = ((lane & 7) ^ (lane >> 3)) * 8;

    f32x4 acc[4][4] = {};

    for (int kt = 0; kt < D_MODEL / 64; ++kt) {
        const int k0 = kt * 64;
        __syncthreads();
#pragma unroll
        for (int t = 0; t < 4; ++t) {
            const int row = w * 32 + t * 8;
            load16_lds(&Ab[(size_t)(i0 + row + sr) * D_MODEL + k0 + scs], &Als[row * 64]);
            load16_lds(&Wob[(size_t)(j0 + row + sr) * D_MODEL + k0 + scs], &Bls[row * 64]);
        }
        __syncthreads();
#pragma unroll
        for (int kh = 0; kh < 2; ++kh) {
            bf16x8 af[4], bfr[4];
#pragma unroll
            for (int mf = 0; mf < 4; ++mf)
                af[mf] = *(const bf16x8*)&Als[lidx(wm * 64 + mf * 16 + fr, kh * 32 + fq * 8)];
#pragma unroll
            for (int nf = 0; nf < 4; ++nf)
                bfr[nf] = *(const bf16x8*)&Bls[lidx(wn * 64 + nf * 16 + fr, kh * 32 + fq * 8)];
#pragma unroll
            for (int mf = 0; mf < 4; ++mf)
#pragma unroll
                for (int nf = 0; nf < 4; ++nf)
                    acc[mf][nf] = __builtin_amdgcn_mfma_f32_16x16x32_bf16(
                        af[mf], bfr[nf], acc[mf][nf], 0, 0, 0);
        }
    }

    float bb[4];
#pragma unroll
    for (int nf = 0; nf < 4; ++nf) bb[nf] = bo[j0 + wn * 64 + nf * 16 + fr];
#pragma unroll
    for (int mf = 0; mf < 4; ++mf)
#pragma unroll
        for (int r = 0; r < 4; ++r) {
            const int i = i0 + wm * 64 + mf * 16 + fq * 4 + r;
#pragma unroll
            for (int nf = 0; nf < 4; ++nf)
                out[(size_t)i * D_MODEL + j0 + wn * 64 + nf * 16 + fr] =
                    acc[mf][nf][r] + bb[nf];
        }
}

// ---------------------------------------------------------------------------
extern "C" void kernel_launch(void* const* d_in, const int* in_sizes, int n_in,
                              void* d_out, int out_size, void* d_ws, size_t ws_size,
                              hipStream_t stream) {
    const float* x     = (const float*)d_in[0];
    // d_in[1]: causal mask (hardcoded in attn_mfma)
    const float* Wq    = (const float*)d_in[2];
    const float* bq    = (const float*)d_in[3];
    const float* Wk    = (const float*)d_in[4];
    const float* bk    = (const float*)d_in[5];
    const float* Wv    = (const float*)d_in[6];
    const float* bv    = (const float*)d_in[7];
    const float* Wo    = (const float*)d_in[8];
    const float* bo    = (const float*)d_in[9];
    const float* scale = (const float*)d_in[10];
    float* out = (float*)d_out;

    const size_t NE = (size_t)MROWS * D_MODEL;  // 8,388,608
    const size_t WE = (size_t)D_MODEL * D_MODEL;

    unsigned short* xb  = (unsigned short*)d_ws;  // reused as AO after qkv
    unsigned short* Qb  = xb + NE;
    unsigned short* Kb  = Qb + NE;
    unsigned short* Vt  = Kb + NE;
    unsigned short* wqb = Vt + NE;
    unsigned short* wkb = wqb + WE;
    unsigned short* wvb = wkb + WE;
    unsigned short* wob = wvb + WE;
    unsigned short* AO  = xb;   // x dead after qkv

    cvt_bf16<<<(int)(NE / 4 / 256), 256, 0, stream>>>(x, xb, (int)(NE / 4));
    cvt_bf16<<<(int)(WE / 4 / 256), 256, 0, stream>>>(Wq, wqb, (int)(WE / 4));
    cvt_bf16<<<(int)(WE / 4 / 256), 256, 0, stream>>>(Wk, wkb, (int)(WE / 4));
    cvt_bf16<<<(int)(WE / 4 / 256), 256, 0, stream>>>(Wv, wvb, (int)(WE / 4));
    cvt_bf16<<<(int)(WE / 4 / 256), 256, 0, stream>>>(Wo, wob, (int)(WE / 4));

    qkv_mfma<<<dim3(MROWS / 128, D_MODEL / 128, 3), 256, 0, stream>>>(
        xb, wqb, bq, wkb, bk, wvb, bv, scale, Qb, Kb, Vt);

    attn_mfma<<<dim3(LSEQ / 64, NHEAD, BATCH), 256, 0, stream>>>(Qb, Kb, Vt, AO);

    oproj_mfma<<<dim3(MROWS / 128, D_MODEL / 128), 256, 0, stream>>>(AO, wob, bo, out);
}

// Round 6
// 404.825 us; speedup vs baseline: 1.0054x; 1.0054x over previous
//
#include <hip/hip_runtime.h>
#include <cstdint>

#define D_MODEL 1024
#define NHEAD 16
#define HEAD_DIM 64
#define LSEQ 2048
#define BATCH 4
#define MROWS (BATCH * LSEQ)  // 8192

typedef __bf16 bf16x8 __attribute__((ext_vector_type(8)));
typedef float f32x4 __attribute__((ext_vector_type(4)));

// fp32 -> bf16 RNE
__device__ __forceinline__ unsigned short f2bf(float f) {
    unsigned b = __builtin_bit_cast(unsigned, f);
    b += 0x7FFFu + ((b >> 16) & 1u);
    return (unsigned short)(b >> 16);
}

// async global->LDS, 16B per lane; lds must be wave-uniform base (lane*16 added by HW)
__device__ __forceinline__ void load16_lds(const void* g, void* lds) {
    __builtin_amdgcn_global_load_lds(
        (const __attribute__((address_space(1))) void*)(uintptr_t)g,
        (__attribute__((address_space(3))) void*)(unsigned)(uintptr_t)lds,
        16, 0, 0);
}

// Swizzled ushort index into a [rows][64]-ushort (128B-row) LDS tile.
__device__ __forceinline__ int lidx(int row, int col /*ushort units*/) {
    return row * 64 + (col ^ ((row & 7) << 3));
}

// ---------------------------------------------------------------------------
// One fused cast launch: x (NE) + Wq,Wk,Wv,Wo (WE each), fp32 -> bf16.
// ---------------------------------------------------------------------------
__global__ __launch_bounds__(256) void cvt_all(
    const float* __restrict__ x, const float* __restrict__ wq,
    const float* __restrict__ wk, const float* __restrict__ wv,
    const float* __restrict__ wo,
    unsigned short* __restrict__ xb, unsigned short* __restrict__ wqb,
    unsigned short* __restrict__ wkb, unsigned short* __restrict__ wvb,
    unsigned short* __restrict__ wob)
{
    const int NE4 = (MROWS * D_MODEL) / 4;    // 2097152
    const int WE4 = (D_MODEL * D_MODEL) / 4;  // 262144 = 2^18
    int i = blockIdx.x * 256 + threadIdx.x;
    const float* src; unsigned short* dst; int off;
    if (i < NE4) { src = x; dst = xb; off = i; }
    else {
        int j = i - NE4;
        int seg = j >> 18;
        off = j & (WE4 - 1);
        src = (seg == 0) ? wq : (seg == 1) ? wk : (seg == 2) ? wv : wo;
        dst = (seg == 0) ? wqb : (seg == 1) ? wkb : (seg == 2) ? wvb : wob;
    }
    float4 v = ((const float4*)src)[off];
    ushort4 o;
    o.x = f2bf(v.x); o.y = f2bf(v.y); o.z = f2bf(v.z); o.w = f2bf(v.w);
    ((ushort4*)dst)[off] = o;
}

// ---------------------------------------------------------------------------
// QKV projection: C = X @ W^T + b, 128x128 tile, BK=64, 4 waves, MFMA 16x16x32.
// z = 0/1/2 -> Q/K/V.  Q,K: fused per-head L2norm * scale (Q also * hd^-0.5),
// layout [B,H,L,64].  V: written transposed [B,H,64,L].
// ---------------------------------------------------------------------------
__global__ __launch_bounds__(256) void qkv_mfma(
    const unsigned short* __restrict__ xb,
    const unsigned short* __restrict__ Wqb, const float* __restrict__ bq,
    const unsigned short* __restrict__ Wkb, const float* __restrict__ bk,
    const unsigned short* __restrict__ Wvb, const float* __restrict__ bv,
    const float* __restrict__ scale,
    unsigned short* __restrict__ Qo, unsigned short* __restrict__ Ko,
    unsigned short* __restrict__ Vt)
{
    __shared__ __align__(16) unsigned short Als[128 * 64];
    __shared__ __align__(16) unsigned short Bls[128 * 64];

    const int z = blockIdx.z;
    const unsigned short* Wb = (z == 0) ? Wqb : (z == 1) ? Wkb : Wvb;
    const float* bias        = (z == 0) ? bq  : (z == 1) ? bk  : bv;

    const int tid = threadIdx.x;
    const int w = tid >> 6, lane = tid & 63;
    const int wm = w >> 1, wn = w & 1;
    const int fr = lane & 15, fq = lane >> 4;
    const int i0 = blockIdx.x * 128, j0 = blockIdx.y * 128;

    const int sr = lane >> 3;
    const int scs = ((lane & 7) ^ (lane >> 3)) * 8;  // inverse-swizzled col (ushorts)

    f32x4 acc[4][4] = {};

    for (int kt = 0; kt < D_MODEL / 64; ++kt) {
        const int k0 = kt * 64;
        __syncthreads();
#pragma unroll
        for (int t = 0; t < 4; ++t) {
            const int row = w * 32 + t * 8;
            load16_lds(&xb[(size_t)(i0 + row + sr) * D_MODEL + k0 + scs], &Als[row * 64]);
            load16_lds(&Wb[(size_t)(j0 + row + sr) * D_MODEL + k0 + scs], &Bls[row * 64]);
        }
        __syncthreads();
#pragma unroll
        for (int kh = 0; kh < 2; ++kh) {
            bf16x8 af[4], bfr[4];
#pragma unroll
            for (int mf = 0; mf < 4; ++mf)
                af[mf] = *(const bf16x8*)&Als[lidx(wm * 64 + mf * 16 + fr, kh * 32 + fq * 8)];
#pragma unroll
            for (int nf = 0; nf < 4; ++nf)
                bfr[nf] = *(const bf16x8*)&Bls[lidx(wn * 64 + nf * 16 + fr, kh * 32 + fq * 8)];
#pragma unroll
            for (int mf = 0; mf < 4; ++mf)
#pragma unroll
                for (int nf = 0; nf < 4; ++nf)
                    acc[mf][nf] = __builtin_amdgcn_mfma_f32_16x16x32_bf16(
                        af[mf], bfr[nf], acc[mf][nf], 0, 0, 0);
        }
    }

    float bb[4];
#pragma unroll
    for (int nf = 0; nf < 4; ++nf) bb[nf] = bias[j0 + wn * 64 + nf * 16 + fr];
#pragma unroll
    for (int mf = 0; mf < 4; ++mf)
#pragma unroll
        for (int nf = 0; nf < 4; ++nf)
#pragma unroll
            for (int r = 0; r < 4; ++r) acc[mf][nf][r] += bb[nf];

    const int h = (j0 >> 6) + wn;  // head index of this wave's 64-col span

    if (z < 2) {
        const float sclr = scale[0] * ((z == 0) ? 0.125f : 1.0f);  // fold hd^-0.5 into Q
        unsigned short* out = (z == 0) ? Qo : Ko;
#pragma unroll
        for (int mf = 0; mf < 4; ++mf) {
#pragma unroll
            for (int r = 0; r < 4; ++r) {
                float ss = 0.f;
#pragma unroll
                for (int nf = 0; nf < 4; ++nf) ss += acc[mf][nf][r] * acc[mf][nf][r];
                ss += __shfl_xor(ss, 1); ss += __shfl_xor(ss, 2);
                ss += __shfl_xor(ss, 4); ss += __shfl_xor(ss, 8);
                const float inv = sclr / fmaxf(sqrtf(ss), 1e-12f);
                const int i = i0 + wm * 64 + mf * 16 + fq * 4 + r;
                const int bidx = i >> 11, lrow = i & (LSEQ - 1);
                const size_t rb = (((size_t)(bidx * NHEAD + h)) * LSEQ + lrow) * HEAD_DIM;
#pragma unroll
                for (int nf = 0; nf < 4; ++nf)
                    out[rb + nf * 16 + fr] = f2bf(acc[mf][nf][r] * inv);
            }
        }
    } else {
#pragma unroll
        for (int mf = 0; mf < 4; ++mf) {
            const int i = i0 + wm * 64 + mf * 16 + fq * 4;  // r=0 row; +r contiguous
            const int bidx = i >> 11, lrow = i & (LSEQ - 1);
#pragma unroll
            for (int nf = 0; nf < 4; ++nf) {
                const int d = nf * 16 + fr;
                const size_t a = (((size_t)(bidx * NHEAD + h)) * HEAD_DIM + d) * LSEQ + lrow;
                ushort4 pk;
                pk.x = f2bf(acc[mf][nf][0]); pk.y = f2bf(acc[mf][nf][1]);
                pk.z = f2bf(acc[mf][nf][2]); pk.w = f2bf(acc[mf][nf][3]);
                *(ushort4*)&Vt[a] = pk;
            }
        }
    }
}

// ---------------------------------------------------------------------------
// Causal flash attention, bf16 MFMA, 2-phase pipelined staging + defer-max
// + s_setprio around MFMA clusters (T5).
// grid=(L/64, H, B) with qt REVERSED (long blocks first); 256 threads, 4 waves.
// ---------------------------------------------------------------------------
__global__ __launch_bounds__(256) void attn_mfma(
    const unsigned short* __restrict__ Qb, const unsigned short* __restrict__ Kb,
    const unsigned short* __restrict__ Vt, unsigned short* __restrict__ AO)
{
    __shared__ __align__(16) unsigned short Kls[2][64 * 64];
    __shared__ __align__(16) unsigned short Vls[2][64 * 64];
    __shared__ __align__(16) unsigned short Pls[4][16 * 64];

    const int qt = gridDim.x - 1 - blockIdx.x;  // longest blocks dispatch first
    const int h = blockIdx.y, b = blockIdx.z;
    const int tid = threadIdx.x, w = tid >> 6, lane = tid & 63;
    const int fr = lane & 15, fq = lane >> 4;

    const size_t hb = (size_t)(b * NHEAD + h);
    const unsigned short* Kg = Kb + hb * LSEQ * HEAD_DIM;
    const unsigned short* Vg = Vt + hb * HEAD_DIM * LSEQ;
    const unsigned short* Qg = Qb + hb * LSEQ * HEAD_DIM;

    const int sr = lane >> 3;
    const int scs = ((lane & 7) ^ sr) * 8;  // pre-swizzled source col

    bf16x8 qf[2];
    {
        const int qrow = qt * 64 + w * 16 + fr;
        qf[0] = *(const bf16x8*)&Qg[(size_t)qrow * HEAD_DIM + fq * 8];
        qf[1] = *(const bf16x8*)&Qg[(size_t)qrow * HEAD_DIM + 32 + fq * 8];
    }

    f32x4 acc_o[4] = {};
    float m_[4], ls[4];
#pragma unroll
    for (int r = 0; r < 4; ++r) { m_[r] = -INFINITY; ls[r] = 0.f; }

#define STAGE(buf, kt_) do {                                                    \
    const unsigned short* gk_ = Kg + (size_t)(kt_) * 64 * HEAD_DIM;             \
    _Pragma("unroll")                                                           \
    for (int t_ = 0; t_ < 2; ++t_) {                                            \
        const int c_ = w * 2 + t_;                                              \
        load16_lds(gk_ + (size_t)(c_ * 8 + sr) * 64 + scs,                      \
                   &Kls[buf][c_ * 8 * 64]);                                     \
        load16_lds(Vg + (size_t)(c_ * 8 + sr) * LSEQ + (kt_) * 64 + scs,        \
                   &Vls[buf][c_ * 8 * 64]);                                     \
    } } while (0)

    STAGE(0, 0);
    __syncthreads();

    int cur = 0;
    for (int kt = 0; kt <= qt; ++kt) {
        // issue next tile's loads before computing this one (overlap)
        if (kt < qt) STAGE(cur ^ 1, kt + 1);

        // S = Q K^T (this wave's 16 rows x 64 keys)
        f32x4 s[4] = {};
        __builtin_amdgcn_s_setprio(1);
#pragma unroll
        for (int nf = 0; nf < 4; ++nf) {
            bf16x8 k0 = *(const bf16x8*)&Kls[cur][lidx(nf * 16 + fr, fq * 8)];
            bf16x8 k1 = *(const bf16x8*)&Kls[cur][lidx(nf * 16 + fr, 32 + fq * 8)];
            s[nf] = __builtin_amdgcn_mfma_f32_16x16x32_bf16(qf[0], k0, s[nf], 0, 0, 0);
            s[nf] = __builtin_amdgcn_mfma_f32_16x16x32_bf16(qf[1], k1, s[nf], 0, 0, 0);
        }
        __builtin_amdgcn_s_setprio(0);

        if (kt == qt) {  // diagonal tile: mask kv > q
#pragma unroll
            for (int nf = 0; nf < 4; ++nf)
#pragma unroll
                for (int r = 0; r < 4; ++r)
                    if (nf * 16 + fr > w * 16 + fq * 4 + r) s[nf][r] = -INFINITY;
        }

        // per-row tile max (16 lanes share a row)
        float v[4];
#pragma unroll
        for (int r = 0; r < 4; ++r) {
            float t = fmaxf(fmaxf(s[0][r], s[1][r]), fmaxf(s[2][r], s[3][r]));
            t = fmaxf(t, __shfl_xor(t, 1));
            t = fmaxf(t, __shfl_xor(t, 2));
            t = fmaxf(t, __shfl_xor(t, 4));
            t = fmaxf(t, __shfl_xor(t, 8));
            v[r] = t;
        }
        // defer-max: skip rescale unless some row's max grew past m+8
        const bool okl = (v[0] <= m_[0] + 8.f) && (v[1] <= m_[1] + 8.f) &&
                         (v[2] <= m_[2] + 8.f) && (v[3] <= m_[3] + 8.f);
        if (!__all(okl)) {
#pragma unroll
            for (int r = 0; r < 4; ++r) {
                const float mn = fmaxf(m_[r], v[r]);
                const float f = __expf(m_[r] - mn);  // -inf -> 0
                m_[r] = mn;
                ls[r] *= f;
                acc_o[0][r] *= f; acc_o[1][r] *= f;
                acc_o[2][r] *= f; acc_o[3][r] *= f;
            }
        }

        float ps[4] = {0.f, 0.f, 0.f, 0.f};
#pragma unroll
        for (int nf = 0; nf < 4; ++nf)
#pragma unroll
            for (int r = 0; r < 4; ++r) {
                const float p = __expf(s[nf][r] - m_[r]);
                s[nf][r] = p;
                ps[r] += p;
            }
#pragma unroll
        for (int r = 0; r < 4; ++r) {
            float t = ps[r];
            t += __shfl_xor(t, 1); t += __shfl_xor(t, 2);
            t += __shfl_xor(t, 4); t += __shfl_xor(t, 8);
            ls[r] += t;
        }

        // P -> LDS (bf16, swizzled) ; row = fq*4+r, col = nf*16+fr
#pragma unroll
        for (int nf = 0; nf < 4; ++nf)
#pragma unroll
            for (int r = 0; r < 4; ++r)
                Pls[w][lidx(fq * 4 + r, nf * 16 + fr)] = f2bf(s[nf][r]);

        // O += P @ V   (A-frag from Pls, B-frag from V^T tile)
        __builtin_amdgcn_s_setprio(1);
#pragma unroll
        for (int kf = 0; kf < 2; ++kf) {
            bf16x8 pa = *(const bf16x8*)&Pls[w][lidx(fr, kf * 32 + fq * 8)];
#pragma unroll
            for (int nf = 0; nf < 4; ++nf) {
                bf16x8 vb = *(const bf16x8*)&Vls[cur][lidx(nf * 16 + fr, kf * 32 + fq * 8)];
                acc_o[nf] = __builtin_amdgcn_mfma_f32_16x16x32_bf16(pa, vb, acc_o[nf], 0, 0, 0);
            }
        }
        __builtin_amdgcn_s_setprio(0);

        __syncthreads();  // drains STAGE vmcnt + protects both LDS buffers
        cur ^= 1;
    }
#undef STAGE

#pragma unroll
    for (int r = 0; r < 4; ++r) {
        const float inv = 1.f / ls[r];
        const int lq = qt * 64 + w * 16 + fq * 4 + r;
        const size_t rb = ((size_t)b * LSEQ + lq) * D_MODEL + h * HEAD_DIM;
#pragma unroll
        for (int nf = 0; nf < 4; ++nf)
            AO[rb + nf * 16 + fr] = f2bf(acc_o[nf][r] * inv);
    }
}

// ---------------------------------------------------------------------------
// Output projection: out = AO @ Wo^T + bo, fp32 output.
// ---------------------------------------------------------------------------
__global__ __launch_bounds__(256) void oproj_mfma(
    const unsigned short* __restrict__ Ab, const unsigned short* __restrict__ Wob,
    const float* __restrict__ bo, float* __restrict__ out)
{
    __shared__ __align__(16) unsigned short Als[128 * 64];
    __shared__ __align__(16) unsigned short Bls[128 * 64];

    const int tid = threadIdx.x;
    const int w = tid >> 6, lane = tid & 63;
    const int wm = w >> 1, wn = w & 1;
    const int fr = lane & 15, fq = lane >> 4;
    const int i0 = blockIdx.x * 128, j0 = blockIdx.y * 128;

    const int sr = lane >> 3;
    const int scs = ((lane & 7) ^ (lane >> 3)) * 8;

    f32x4 acc[4][4] = {};

    for (int kt = 0; kt < D_MODEL / 64; ++kt) {
        const int k0 = kt * 64;
        __syncthreads();
#pragma unroll
        for (int t = 0; t < 4; ++t) {
            const int row = w * 32 + t * 8;
            load16_lds(&Ab[(size_t)(i0 + row + sr) * D_MODEL + k0 + scs], &Als[row * 64]);
            load16_lds(&Wob[(size_t)(j0 + row + sr) * D_MODEL + k0 + scs], &Bls[row * 64]);
        }
        __syncthreads();
#pragma unroll
        for (int kh = 0; kh < 2; ++kh) {
            bf16x8 af[4], bfr[4];
#pragma unroll
            for (int mf = 0; mf < 4; ++mf)
                af[mf] = *(const bf16x8*)&Als[lidx(wm * 64 + mf * 16 + fr, kh * 32 + fq * 8)];
#pragma unroll
            for (int nf = 0; nf < 4; ++nf)
                bfr[nf] = *(const bf16x8*)&Bls[lidx(wn * 64 + nf * 16 + fr, kh * 32 + fq * 8)];
#pragma unroll
            for (int mf = 0; mf < 4; ++mf)
#pragma unroll
                for (int nf = 0; nf < 4; ++nf)
                    acc[mf][nf] = __builtin_amdgcn_mfma_f32_16x16x32_bf16(
                        af[mf], bfr[nf], acc[mf][nf], 0, 0, 0);
        }
    }

    float bb[4];
#pragma unroll
    for (int nf = 0; nf < 4; ++nf) bb[nf] = bo[j0 + wn * 64 + nf * 16 + fr];
#pragma unroll
    for (int mf = 0; mf < 4; ++mf)
#pragma unroll
        for (int r = 0; r < 4; ++r) {
            const int i = i0 + wm * 64 + mf * 16 + fq * 4 + r;
#pragma unroll
            for (int nf = 0; nf < 4; ++nf)
                out[(size_t)i * D_MODEL + j0 + wn * 64 + nf * 16 + fr] =
                    acc[mf][nf][r] + bb[nf];
        }
}

// ---------------------------------------------------------------------------
extern "C" void kernel_launch(void* const* d_in, const int* in_sizes, int n_in,
                              void* d_out, int out_size, void* d_ws, size_t ws_size,
                              hipStream_t stream) {
    const float* x     = (const float*)d_in[0];
    // d_in[1]: causal mask (hardcoded in attn_mfma)
    const float* Wq    = (const float*)d_in[2];
    const float* bq    = (const float*)d_in[3];
    const float* Wk    = (const float*)d_in[4];
    const float* bk    = (const float*)d_in[5];
    const float* Wv    = (const float*)d_in[6];
    const float* bv    = (const float*)d_in[7];
    const float* Wo    = (const float*)d_in[8];
    const float* bo    = (const float*)d_in[9];
    const float* scale = (const float*)d_in[10];
    float* out = (float*)d_out;

    const size_t NE = (size_t)MROWS * D_MODEL;  // 8,388,608
    const size_t WE = (size_t)D_MODEL * D_MODEL;

    unsigned short* xb  = (unsigned short*)d_ws;  // reused as AO after qkv
    unsigned short* Qb  = xb + NE;
    unsigned short* Kb  = Qb + NE;
    unsigned short* Vt  = Kb + NE;
    unsigned short* wqb = Vt + NE;
    unsigned short* wkb = wqb + WE;
    unsigned short* wvb = wkb + WE;
    unsigned short* wob = wvb + WE;
    unsigned short* AO  = xb;   // x dead after qkv

    {
        const int total4 = (int)((NE + 4 * WE) / 4);  // 3,145,728
        cvt_all<<<total4 / 256, 256, 0, stream>>>(x, Wq, Wk, Wv, Wo,
                                                  xb, wqb, wkb, wvb, wob);
    }

    qkv_mfma<<<dim3(MROWS / 128, D_MODEL / 128, 3), 256, 0, stream>>>(
        xb, wqb, bq, wkb, bk, wvb, bv, scale, Qb, Kb, Vt);

    attn_mfma<<<dim3(LSEQ / 64, NHEAD, BATCH), 256, 0, stream>>>(Qb, Kb, Vt, AO);

    oproj_mfma<<<dim3(MROWS / 128, D_MODEL / 128), 256, 0, stream>>>(AO, wob, bo, out);
}

// Round 7
// 390.603 us; speedup vs baseline: 1.0420x; 1.0364x over previous
//
#include <hip/hip_runtime.h>
#include <cstdint>

#define D_MODEL 1024
#define NHEAD 16
#define HEAD_DIM 64
#define LSEQ 2048
#define BATCH 4
#define MROWS (BATCH * LSEQ)  // 8192

typedef __bf16 bf16x8 __attribute__((ext_vector_type(8)));
typedef float f32x4 __attribute__((ext_vector_type(4)));

// fp32 -> bf16 RNE
__device__ __forceinline__ unsigned short f2bf(float f) {
    unsigned b = __builtin_bit_cast(unsigned, f);
    b += 0x7FFFu + ((b >> 16) & 1u);
    return (unsigned short)(b >> 16);
}

// async global->LDS, 16B per lane; lds must be wave-uniform base (lane*16 added by HW)
__device__ __forceinline__ void load16_lds(const void* g, void* lds) {
    __builtin_amdgcn_global_load_lds(
        (const __attribute__((address_space(1))) void*)(uintptr_t)g,
        (__attribute__((address_space(3))) void*)(unsigned)(uintptr_t)lds,
        16, 0, 0);
}

// Swizzled ushort index into a [rows][64]-ushort (128B-row) LDS tile.
__device__ __forceinline__ int lidx(int row, int col /*ushort units*/) {
    return row * 64 + (col ^ ((row & 7) << 3));
}

// ---------------------------------------------------------------------------
// One fused cast launch: x (NE) + Wq,Wk,Wv,Wo (WE each), fp32 -> bf16.
// ---------------------------------------------------------------------------
__global__ __launch_bounds__(256) void cvt_all(
    const float* __restrict__ x, const float* __restrict__ wq,
    const float* __restrict__ wk, const float* __restrict__ wv,
    const float* __restrict__ wo,
    unsigned short* __restrict__ xb, unsigned short* __restrict__ wqb,
    unsigned short* __restrict__ wkb, unsigned short* __restrict__ wvb,
    unsigned short* __restrict__ wob)
{
    const int NE4 = (MROWS * D_MODEL) / 4;    // 2097152
    const int WE4 = (D_MODEL * D_MODEL) / 4;  // 262144 = 2^18
    int i = blockIdx.x * 256 + threadIdx.x;
    const float* src; unsigned short* dst; int off;
    if (i < NE4) { src = x; dst = xb; off = i; }
    else {
        int j = i - NE4;
        int seg = j >> 18;
        off = j & (WE4 - 1);
        src = (seg == 0) ? wq : (seg == 1) ? wk : (seg == 2) ? wv : wo;
        dst = (seg == 0) ? wqb : (seg == 1) ? wkb : (seg == 2) ? wvb : wob;
    }
    float4 v = ((const float4*)src)[off];
    ushort4 o;
    o.x = f2bf(v.x); o.y = f2bf(v.y); o.z = f2bf(v.z); o.w = f2bf(v.w);
    ((ushort4*)dst)[off] = o;
}

// ---------------------------------------------------------------------------
// QKV projection: C = X @ W^T + b, 128x128 tile, BK=64, 4 waves, MFMA 16x16x32.
// z = 0/1/2 -> Q/K/V.  Q,K: fused per-head L2norm * scale (Q also * hd^-0.5),
// layout [B,H,L,64].  V: written transposed [B,H,64,L].
// ---------------------------------------------------------------------------
__global__ __launch_bounds__(256) void qkv_mfma(
    const unsigned short* __restrict__ xb,
    const unsigned short* __restrict__ Wqb, const float* __restrict__ bq,
    const unsigned short* __restrict__ Wkb, const float* __restrict__ bk,
    const unsigned short* __restrict__ Wvb, const float* __restrict__ bv,
    const float* __restrict__ scale,
    unsigned short* __restrict__ Qo, unsigned short* __restrict__ Ko,
    unsigned short* __restrict__ Vt)
{
    __shared__ __align__(16) unsigned short Als[128 * 64];
    __shared__ __align__(16) unsigned short Bls[128 * 64];

    const int z = blockIdx.z;
    const unsigned short* Wb = (z == 0) ? Wqb : (z == 1) ? Wkb : Wvb;
    const float* bias        = (z == 0) ? bq  : (z == 1) ? bk  : bv;

    const int tid = threadIdx.x;
    const int w = tid >> 6, lane = tid & 63;
    const int wm = w >> 1, wn = w & 1;
    const int fr = lane & 15, fq = lane >> 4;
    const int i0 = blockIdx.x * 128, j0 = blockIdx.y * 128;

    const int sr = lane >> 3;
    const int scs = ((lane & 7) ^ (lane >> 3)) * 8;  // inverse-swizzled col (ushorts)

    f32x4 acc[4][4] = {};

    for (int kt = 0; kt < D_MODEL / 64; ++kt) {
        const int k0 = kt * 64;
        __syncthreads();
#pragma unroll
        for (int t = 0; t < 4; ++t) {
            const int row = w * 32 + t * 8;
            load16_lds(&xb[(size_t)(i0 + row + sr) * D_MODEL + k0 + scs], &Als[row * 64]);
            load16_lds(&Wb[(size_t)(j0 + row + sr) * D_MODEL + k0 + scs], &Bls[row * 64]);
        }
        __syncthreads();
#pragma unroll
        for (int kh = 0; kh < 2; ++kh) {
            bf16x8 af[4], bfr[4];
#pragma unroll
            for (int mf = 0; mf < 4; ++mf)
                af[mf] = *(const bf16x8*)&Als[lidx(wm * 64 + mf * 16 + fr, kh * 32 + fq * 8)];
#pragma unroll
            for (int nf = 0; nf < 4; ++nf)
                bfr[nf] = *(const bf16x8*)&Bls[lidx(wn * 64 + nf * 16 + fr, kh * 32 + fq * 8)];
#pragma unroll
            for (int mf = 0; mf < 4; ++mf)
#pragma unroll
                for (int nf = 0; nf < 4; ++nf)
                    acc[mf][nf] = __builtin_amdgcn_mfma_f32_16x16x32_bf16(
                        af[mf], bfr[nf], acc[mf][nf], 0, 0, 0);
        }
    }

    float bb[4];
#pragma unroll
    for (int nf = 0; nf < 4; ++nf) bb[nf] = bias[j0 + wn * 64 + nf * 16 + fr];
#pragma unroll
    for (int mf = 0; mf < 4; ++mf)
#pragma unroll
        for (int nf = 0; nf < 4; ++nf)
#pragma unroll
            for (int r = 0; r < 4; ++r) acc[mf][nf][r] += bb[nf];

    const int h = (j0 >> 6) + wn;  // head index of this wave's 64-col span

    if (z < 2) {
        const float sclr = scale[0] * ((z == 0) ? 0.125f : 1.0f);  // fold hd^-0.5 into Q
        unsigned short* out = (z == 0) ? Qo : Ko;
#pragma unroll
        for (int mf = 0; mf < 4; ++mf) {
#pragma unroll
            for (int r = 0; r < 4; ++r) {
                float ss = 0.f;
#pragma unroll
                for (int nf = 0; nf < 4; ++nf) ss += acc[mf][nf][r] * acc[mf][nf][r];
                ss += __shfl_xor(ss, 1); ss += __shfl_xor(ss, 2);
                ss += __shfl_xor(ss, 4); ss += __shfl_xor(ss, 8);
                const float inv = sclr / fmaxf(sqrtf(ss), 1e-12f);
                const int i = i0 + wm * 64 + mf * 16 + fq * 4 + r;
                const int bidx = i >> 11, lrow = i & (LSEQ - 1);
                const size_t rb = (((size_t)(bidx * NHEAD + h)) * LSEQ + lrow) * HEAD_DIM;
#pragma unroll
                for (int nf = 0; nf < 4; ++nf)
                    out[rb + nf * 16 + fr] = f2bf(acc[mf][nf][r] * inv);
            }
        }
    } else {
#pragma unroll
        for (int mf = 0; mf < 4; ++mf) {
            const int i = i0 + wm * 64 + mf * 16 + fq * 4;  // r=0 row; +r contiguous
            const int bidx = i >> 11, lrow = i & (LSEQ - 1);
#pragma unroll
            for (int nf = 0; nf < 4; ++nf) {
                const int d = nf * 16 + fr;
                const size_t a = (((size_t)(bidx * NHEAD + h)) * HEAD_DIM + d) * LSEQ + lrow;
                ushort4 pk;
                pk.x = f2bf(acc[mf][nf][0]); pk.y = f2bf(acc[mf][nf][1]);
                pk.z = f2bf(acc[mf][nf][2]); pk.w = f2bf(acc[mf][nf][3]);
                *(ushort4*)&Vt[a] = pk;
            }
        }
    }
}

// ---------------------------------------------------------------------------
// Causal flash attention, bf16 MFMA.  8 waves (512 thr), QBLK=128 (wave w owns
// rows w*16..w*16+15), KVBLK=64 double-buffered.  48 KB LDS -> 3 blocks/CU =
// 24 waves/CU (occupancy was the round-6 diagnosis).  Per-wave causal skip;
// defer-max; swizzled LDS; one barrier per KV tile.
// grid = (L/128 reversed, H, B).
// ---------------------------------------------------------------------------
__global__ __launch_bounds__(512) void attn_mfma(
    const unsigned short* __restrict__ Qb, const unsigned short* __restrict__ Kb,
    const unsigned short* __restrict__ Vt, unsigned short* __restrict__ AO)
{
    __shared__ __align__(16) unsigned short Kls[2][64 * 64];
    __shared__ __align__(16) unsigned short Vls[2][64 * 64];
    __shared__ __align__(16) unsigned short Pls[8][16 * 64];

    const int qt = gridDim.x - 1 - blockIdx.x;  // longest blocks dispatch first
    const int h = blockIdx.y, b = blockIdx.z;
    const int tid = threadIdx.x, w = tid >> 6, lane = tid & 63;
    const int fr = lane & 15, fq = lane >> 4;

    const size_t hb = (size_t)(b * NHEAD + h);
    const unsigned short* Kg = Kb + hb * LSEQ * HEAD_DIM;
    const unsigned short* Vg = Vt + hb * HEAD_DIM * LSEQ;
    const unsigned short* Qg = Qb + hb * LSEQ * HEAD_DIM;

    const int sr = lane >> 3;
    const int scs = ((lane & 7) ^ sr) * 8;  // pre-swizzled source col (ushorts)

    const int qr0 = qt * 128 + w * 16;      // wave's first q row

    bf16x8 qf[2];
    {
        const int qrow = qr0 + fr;
        qf[0] = *(const bf16x8*)&Qg[(size_t)qrow * HEAD_DIM + fq * 8];
        qf[1] = *(const bf16x8*)&Qg[(size_t)qrow * HEAD_DIM + 32 + fq * 8];
    }

    f32x4 acc_o[4] = {};
    float m_[4], ls[4];
#pragma unroll
    for (int r = 0; r < 4; ++r) { m_[r] = -INFINITY; ls[r] = 0.f; }

    // stage: wave w loads K rows [w*8, w*8+8) and V d-rows [w*8, w*8+8)
#define STAGE(buf, kt_) do {                                                     \
    load16_lds(Kg + (size_t)((kt_) * 64 + w * 8 + sr) * HEAD_DIM + scs,          \
               &Kls[buf][w * 8 * 64]);                                           \
    load16_lds(Vg + (size_t)(w * 8 + sr) * LSEQ + (kt_) * 64 + scs,              \
               &Vls[buf][w * 8 * 64]);                                           \
    } while (0)

    const int nk = 2 * qt + 2;  // KV tiles covering this block's causal span
    STAGE(0, 0);
    __syncthreads();

    int cur = 0;
    for (int kt = 0; kt < nk; ++kt) {
        if (kt < nk - 1) STAGE(cur ^ 1, kt + 1);

        if (kt * 64 <= qr0 + 15) {  // wave has unmasked keys in this tile
            // S = Q K^T (wave's 16 rows x 64 keys)
            f32x4 s[4] = {};
            __builtin_amdgcn_s_setprio(1);
#pragma unroll
            for (int nf = 0; nf < 4; ++nf) {
                bf16x8 k0 = *(const bf16x8*)&Kls[cur][lidx(nf * 16 + fr, fq * 8)];
                bf16x8 k1 = *(const bf16x8*)&Kls[cur][lidx(nf * 16 + fr, 32 + fq * 8)];
                s[nf] = __builtin_amdgcn_mfma_f32_16x16x32_bf16(qf[0], k0, s[nf], 0, 0, 0);
                s[nf] = __builtin_amdgcn_mfma_f32_16x16x32_bf16(qf[1], k1, s[nf], 0, 0, 0);
            }
            __builtin_amdgcn_s_setprio(0);

            if (kt * 64 + 63 > qr0) {  // diagonal band for this wave: mask kv > q
#pragma unroll
                for (int nf = 0; nf < 4; ++nf)
#pragma unroll
                    for (int r = 0; r < 4; ++r)
                        if (kt * 64 + nf * 16 + fr > qr0 + fq * 4 + r)
                            s[nf][r] = -INFINITY;
            }

            // per-row tile max (16 lanes share a row)
            float v[4];
#pragma unroll
            for (int r = 0; r < 4; ++r) {
                float t = fmaxf(fmaxf(s[0][r], s[1][r]), fmaxf(s[2][r], s[3][r]));
                t = fmaxf(t, __shfl_xor(t, 1));
                t = fmaxf(t, __shfl_xor(t, 2));
                t = fmaxf(t, __shfl_xor(t, 4));
                t = fmaxf(t, __shfl_xor(t, 8));
                v[r] = t;
            }
            // defer-max: skip rescale unless some row's max grew past m+8
            const bool okl = (v[0] <= m_[0] + 8.f) && (v[1] <= m_[1] + 8.f) &&
                             (v[2] <= m_[2] + 8.f) && (v[3] <= m_[3] + 8.f);
            if (!__all(okl)) {
#pragma unroll
                for (int r = 0; r < 4; ++r) {
                    const float mn = fmaxf(m_[r], v[r]);
                    const float f = __expf(m_[r] - mn);  // -inf -> 0
                    m_[r] = mn;
                    ls[r] *= f;
                    acc_o[0][r] *= f; acc_o[1][r] *= f;
                    acc_o[2][r] *= f; acc_o[3][r] *= f;
                }
            }

            float ps[4] = {0.f, 0.f, 0.f, 0.f};
#pragma unroll
            for (int nf = 0; nf < 4; ++nf)
#pragma unroll
                for (int r = 0; r < 4; ++r) {
                    const float p = __expf(s[nf][r] - m_[r]);
                    s[nf][r] = p;
                    ps[r] += p;
                }
#pragma unroll
            for (int r = 0; r < 4; ++r) {
                float t = ps[r];
                t += __shfl_xor(t, 1); t += __shfl_xor(t, 2);
                t += __shfl_xor(t, 4); t += __shfl_xor(t, 8);
                ls[r] += t;
            }

            // P -> LDS (bf16, swizzled) ; row = fq*4+r, col = nf*16+fr
#pragma unroll
            for (int nf = 0; nf < 4; ++nf)
#pragma unroll
                for (int r = 0; r < 4; ++r)
                    Pls[w][lidx(fq * 4 + r, nf * 16 + fr)] = f2bf(s[nf][r]);

            // O += P @ V   (A-frag from Pls, B-frag from V^T tile)
            __builtin_amdgcn_s_setprio(1);
#pragma unroll
            for (int kf = 0; kf < 2; ++kf) {
                bf16x8 pa = *(const bf16x8*)&Pls[w][lidx(fr, kf * 32 + fq * 8)];
#pragma unroll
                for (int nf = 0; nf < 4; ++nf) {
                    bf16x8 vb = *(const bf16x8*)&Vls[cur][lidx(nf * 16 + fr, kf * 32 + fq * 8)];
                    acc_o[nf] = __builtin_amdgcn_mfma_f32_16x16x32_bf16(pa, vb, acc_o[nf], 0, 0, 0);
                }
            }
            __builtin_amdgcn_s_setprio(0);
        }

        __syncthreads();  // drains STAGE vmcnt + protects both LDS buffers
        cur ^= 1;
    }
#undef STAGE

#pragma unroll
    for (int r = 0; r < 4; ++r) {
        const float inv = 1.f / ls[r];
        const int lq = qr0 + fq * 4 + r;
        const size_t rb = ((size_t)b * LSEQ + lq) * D_MODEL + h * HEAD_DIM;
#pragma unroll
        for (int nf = 0; nf < 4; ++nf)
            AO[rb + nf * 16 + fr] = f2bf(acc_o[nf][r] * inv);
    }
}

// ---------------------------------------------------------------------------
// Output projection: out = AO @ Wo^T + bo, fp32 output.
// ---------------------------------------------------------------------------
__global__ __launch_bounds__(256) void oproj_mfma(
    const unsigned short* __restrict__ Ab, const unsigned short* __restrict__ Wob,
    const float* __restrict__ bo, float* __restrict__ out)
{
    __shared__ __align__(16) unsigned short Als[128 * 64];
    __shared__ __align__(16) unsigned short Bls[128 * 64];

    const int tid = threadIdx.x;
    const int w = tid >> 6, lane = tid & 63;
    const int wm = w >> 1, wn = w & 1;
    const int fr = lane & 15, fq = lane >> 4;
    const int i0 = blockIdx.x * 128, j0 = blockIdx.y * 128;

    const int sr = lane >> 3;
    const int scs = ((lane & 7) ^ (lane >> 3)) * 8;

    f32x4 acc[4][4] = {};

    for (int kt = 0; kt < D_MODEL / 64; ++kt) {
        const int k0 = kt * 64;
        __syncthreads();
#pragma unroll
        for (int t = 0; t < 4; ++t) {
            const int row = w * 32 + t * 8;
            load16_lds(&Ab[(size_t)(i0 + row + sr) * D_MODEL + k0 + scs], &Als[row * 64]);
            load16_lds(&Wob[(size_t)(j0 + row + sr) * D_MODEL + k0 + scs], &Bls[row * 64]);
        }
        __syncthreads();
#pragma unroll
        for (int kh = 0; kh < 2; ++kh) {
            bf16x8 af[4], bfr[4];
#pragma unroll
            for (int mf = 0; mf < 4; ++mf)
                af[mf] = *(const bf16x8*)&Als[lidx(wm * 64 + mf * 16 + fr, kh * 32 + fq * 8)];
#pragma unroll
            for (int nf = 0; nf < 4; ++nf)
                bfr[nf] = *(const bf16x8*)&Bls[lidx(wn * 64 + nf * 16 + fr, kh * 32 + fq * 8)];
#pragma unroll
            for (int mf = 0; mf < 4; ++mf)
#pragma unroll
                for (int nf = 0; nf < 4; ++nf)
                    acc[mf][nf] = __builtin_amdgcn_mfma_f32_16x16x32_bf16(
                        af[mf], bfr[nf], acc[mf][nf], 0, 0, 0);
        }
    }

    float bb[4];
#pragma unroll
    for (int nf = 0; nf < 4; ++nf) bb[nf] = bo[j0 + wn * 64 + nf * 16 + fr];
#pragma unroll
    for (int mf = 0; mf < 4; ++mf)
#pragma unroll
        for (int r = 0; r < 4; ++r) {
            const int i = i0 + wm * 64 + mf * 16 + fq * 4 + r;
#pragma unroll
            for (int nf = 0; nf < 4; ++nf)
                out[(size_t)i * D_MODEL + j0 + wn * 64 + nf * 16 + fr] =
                    acc[mf][nf][r] + bb[nf];
        }
}

// ---------------------------------------------------------------------------
extern "C" void kernel_launch(void* const* d_in, const int* in_sizes, int n_in,
                              void* d_out, int out_size, void* d_ws, size_t ws_size,
                              hipStream_t stream) {
    const float* x     = (const float*)d_in[0];
    // d_in[1]: causal mask (hardcoded in attn_mfma)
    const float* Wq    = (const float*)d_in[2];
    const float* bq    = (const float*)d_in[3];
    const float* Wk    = (const float*)d_in[4];
    const float* bk    = (const float*)d_in[5];
    const float* Wv    = (const float*)d_in[6];
    const float* bv    = (const float*)d_in[7];
    const float* Wo    = (const float*)d_in[8];
    const float* bo    = (const float*)d_in[9];
    const float* scale = (const float*)d_in[10];
    float* out = (float*)d_out;

    const size_t NE = (size_t)MROWS * D_MODEL;  // 8,388,608
    const size_t WE = (size_t)D_MODEL * D_MODEL;

    unsigned short* xb  = (unsigned short*)d_ws;  // reused as AO after qkv
    unsigned short* Qb  = xb + NE;
    unsigned short* Kb  = Qb + NE;
    unsigned short* Vt  = Kb + NE;
    unsigned short* wqb = Vt + NE;
    unsigned short* wkb = wqb + WE;
    unsigned short* wvb = wkb + WE;
    unsigned short* wob = wvb + WE;
    unsigned short* AO  = xb;   // x dead after qkv

    {
        const int total4 = (int)((NE + 4 * WE) / 4);  // 3,145,728
        cvt_all<<<total4 / 256, 256, 0, stream>>>(x, Wq, Wk, Wv, Wo,
                                                  xb, wqb, wkb, wvb, wob);
    }

    qkv_mfma<<<dim3(MROWS / 128, D_MODEL / 128, 3), 256, 0, stream>>>(
        xb, wqb, bq, wkb, bk, wvb, bv, scale, Qb, Kb, Vt);

    attn_mfma<<<dim3(LSEQ / 128, NHEAD, BATCH), 512, 0, stream>>>(Qb, Kb, Vt, AO);

    oproj_mfma<<<dim3(MROWS / 128, D_MODEL / 128), 256, 0, stream>>>(AO, wob, bo, out);
}

// Round 9
// 300.858 us; speedup vs baseline: 1.3528x; 1.2983x over previous
//
#include <hip/hip_runtime.h>
#include <cstdint>

#define D_MODEL 1024
#define NHEAD 16
#define HEAD_DIM 64
#define LSEQ 2048
#define BATCH 4
#define MROWS (BATCH * LSEQ)  // 8192

typedef __bf16 bf16x8 __attribute__((ext_vector_type(8)));
typedef float f32x4 __attribute__((ext_vector_type(4)));

// fp32 -> bf16 RNE
__device__ __forceinline__ unsigned short f2bf(float f) {
    unsigned b = __builtin_bit_cast(unsigned, f);
    b += 0x7FFFu + ((b >> 16) & 1u);
    return (unsigned short)(b >> 16);
}

// async global->LDS, 16B per lane; lds must be wave-uniform base (lane*16 added by HW)
__device__ __forceinline__ void load16_lds(const void* g, void* lds) {
    __builtin_amdgcn_global_load_lds(
        (const __attribute__((address_space(1))) void*)(uintptr_t)g,
        (__attribute__((address_space(3))) void*)(unsigned)(uintptr_t)lds,
        16, 0, 0);
}

// Swizzled ushort index into a [rows][64]-ushort (128B-row) LDS tile.
__device__ __forceinline__ int lidx(int row, int col /*ushort units*/) {
    return row * 64 + (col ^ ((row & 7) << 3));
}

// ---------------------------------------------------------------------------
// One fused cast launch: x (NE) + Wq,Wk,Wv,Wo (WE each), fp32 -> bf16.
// ---------------------------------------------------------------------------
__global__ __launch_bounds__(256) void cvt_all(
    const float* __restrict__ x, const float* __restrict__ wq,
    const float* __restrict__ wk, const float* __restrict__ wv,
    const float* __restrict__ wo,
    unsigned short* __restrict__ xb, unsigned short* __restrict__ wqb,
    unsigned short* __restrict__ wkb, unsigned short* __restrict__ wvb,
    unsigned short* __restrict__ wob)
{
    const int NE4 = (MROWS * D_MODEL) / 4;    // 2097152
    const int WE4 = (D_MODEL * D_MODEL) / 4;  // 262144 = 2^18
    int i = blockIdx.x * 256 + threadIdx.x;
    const float* src; unsigned short* dst; int off;
    if (i < NE4) { src = x; dst = xb; off = i; }
    else {
        int j = i - NE4;
        int seg = j >> 18;
        off = j & (WE4 - 1);
        src = (seg == 0) ? wq : (seg == 1) ? wk : (seg == 2) ? wv : wo;
        dst = (seg == 0) ? wqb : (seg == 1) ? wkb : (seg == 2) ? wvb : wob;
    }
    float4 v = ((const float4*)src)[off];
    ushort4 o;
    o.x = f2bf(v.x); o.y = f2bf(v.y); o.z = f2bf(v.z); o.w = f2bf(v.w);
    ((ushort4*)dst)[off] = o;
}

// ---------------------------------------------------------------------------
// QKV projection: C = X @ W^T + b, 128x128 tile, BK=64, 4 waves, MFMA 16x16x32.
// z = 0/1/2 -> Q/K/V.  Q,K: fused per-head L2norm * scale (Q also * hd^-0.5),
// layout [B,H,L,64].  V: written transposed [B,H,64,L].
// ---------------------------------------------------------------------------
__global__ __launch_bounds__(256) void qkv_mfma(
    const unsigned short* __restrict__ xb,
    const unsigned short* __restrict__ Wqb, const float* __restrict__ bq,
    const unsigned short* __restrict__ Wkb, const float* __restrict__ bk,
    const unsigned short* __restrict__ Wvb, const float* __restrict__ bv,
    const float* __restrict__ scale,
    unsigned short* __restrict__ Qo, unsigned short* __restrict__ Ko,
    unsigned short* __restrict__ Vt)
{
    __shared__ __align__(16) unsigned short Als[128 * 64];
    __shared__ __align__(16) unsigned short Bls[128 * 64];

    const int z = blockIdx.z;
    const unsigned short* Wb = (z == 0) ? Wqb : (z == 1) ? Wkb : Wvb;
    const float* bias        = (z == 0) ? bq  : (z == 1) ? bk  : bv;

    const int tid = threadIdx.x;
    const int w = tid >> 6, lane = tid & 63;
    const int wm = w >> 1, wn = w & 1;
    const int fr = lane & 15, fq = lane >> 4;
    const int i0 = blockIdx.x * 128, j0 = blockIdx.y * 128;

    const int sr = lane >> 3;
    const int scs = ((lane & 7) ^ (lane >> 3)) * 8;  // inverse-swizzled col (ushorts)

    f32x4 acc[4][4] = {};

    for (int kt = 0; kt < D_MODEL / 64; ++kt) {
        const int k0 = kt * 64;
        __syncthreads();
#pragma unroll
        for (int t = 0; t < 4; ++t) {
            const int row = w * 32 + t * 8;
            load16_lds(&xb[(size_t)(i0 + row + sr) * D_MODEL + k0 + scs], &Als[row * 64]);
            load16_lds(&Wb[(size_t)(j0 + row + sr) * D_MODEL + k0 + scs], &Bls[row * 64]);
        }
        __syncthreads();
#pragma unroll
        for (int kh = 0; kh < 2; ++kh) {
            bf16x8 af[4], bfr[4];
#pragma unroll
            for (int mf = 0; mf < 4; ++mf)
                af[mf] = *(const bf16x8*)&Als[lidx(wm * 64 + mf * 16 + fr, kh * 32 + fq * 8)];
#pragma unroll
            for (int nf = 0; nf < 4; ++nf)
                bfr[nf] = *(const bf16x8*)&Bls[lidx(wn * 64 + nf * 16 + fr, kh * 32 + fq * 8)];
#pragma unroll
            for (int mf = 0; mf < 4; ++mf)
#pragma unroll
                for (int nf = 0; nf < 4; ++nf)
                    acc[mf][nf] = __builtin_amdgcn_mfma_f32_16x16x32_bf16(
                        af[mf], bfr[nf], acc[mf][nf], 0, 0, 0);
        }
    }

    float bb[4];
#pragma unroll
    for (int nf = 0; nf < 4; ++nf) bb[nf] = bias[j0 + wn * 64 + nf * 16 + fr];
#pragma unroll
    for (int mf = 0; mf < 4; ++mf)
#pragma unroll
        for (int nf = 0; nf < 4; ++nf)
#pragma unroll
            for (int r = 0; r < 4; ++r) acc[mf][nf][r] += bb[nf];

    const int h = (j0 >> 6) + wn;  // head index of this wave's 64-col span

    if (z < 2) {
        const float sclr = scale[0] * ((z == 0) ? 0.125f : 1.0f);  // fold hd^-0.5 into Q
        unsigned short* out = (z == 0) ? Qo : Ko;
#pragma unroll
        for (int mf = 0; mf < 4; ++mf) {
#pragma unroll
            for (int r = 0; r < 4; ++r) {
                float ss = 0.f;
#pragma unroll
                for (int nf = 0; nf < 4; ++nf) ss += acc[mf][nf][r] * acc[mf][nf][r];
                ss += __shfl_xor(ss, 1); ss += __shfl_xor(ss, 2);
                ss += __shfl_xor(ss, 4); ss += __shfl_xor(ss, 8);
                const float inv = sclr / fmaxf(sqrtf(ss), 1e-12f);
                const int i = i0 + wm * 64 + mf * 16 + fq * 4 + r;
                const int bidx = i >> 11, lrow = i & (LSEQ - 1);
                const size_t rb = (((size_t)(bidx * NHEAD + h)) * LSEQ + lrow) * HEAD_DIM;
#pragma unroll
                for (int nf = 0; nf < 4; ++nf)
                    out[rb + nf * 16 + fr] = f2bf(acc[mf][nf][r] * inv);
            }
        }
    } else {
#pragma unroll
        for (int mf = 0; mf < 4; ++mf) {
            const int i = i0 + wm * 64 + mf * 16 + fq * 4;  // r=0 row; +r contiguous
            const int bidx = i >> 11, lrow = i & (LSEQ - 1);
#pragma unroll
            for (int nf = 0; nf < 4; ++nf) {
                const int d = nf * 16 + fr;
                const size_t a = (((size_t)(bidx * NHEAD + h)) * HEAD_DIM + d) * LSEQ + lrow;
                ushort4 pk;
                pk.x = f2bf(acc[mf][nf][0]); pk.y = f2bf(acc[mf][nf][1]);
                pk.z = f2bf(acc[mf][nf][2]); pk.w = f2bf(acc[mf][nf][3]);
                *(ushort4*)&Vt[a] = pk;
            }
        }
    }
}

// ---------------------------------------------------------------------------
// Causal flash attention, bf16 MFMA.  8 waves (512 thr), QBLK=128.
// TRIANGULAR LOAD BALANCE: each block processes TWO q-tiles (qt, 15-qt) for
// its (b,h) -> every block does exactly 34 KV-tile iterations; 512 uniform
// blocks, all co-resident (48 KB LDS -> 3 blocks/CU), no drain tail.
// grid = (512), flat.
// ---------------------------------------------------------------------------
__global__ __launch_bounds__(512) void attn_mfma(
    const unsigned short* __restrict__ Qb, const unsigned short* __restrict__ Kb,
    const unsigned short* __restrict__ Vt, unsigned short* __restrict__ AO)
{
    __shared__ __align__(16) unsigned short Kls[2][64 * 64];
    __shared__ __align__(16) unsigned short Vls[2][64 * 64];
    __shared__ __align__(16) unsigned short Pls[8][16 * 64];

    const int pid = blockIdx.x;
    const int u = pid >> 6;           // 0..7  -> qt pair (15-u, u)
    const int hb = pid & 63;          // (b,h)
    const int h = hb & 15, b = hb >> 4;
    const int tid = threadIdx.x, w = tid >> 6, lane = tid & 63;
    const int fr = lane & 15, fq = lane >> 4;

    const size_t hbs = (size_t)(b * NHEAD + h);
    const unsigned short* Kg = Kb + hbs * LSEQ * HEAD_DIM;
    const unsigned short* Vg = Vt + hbs * HEAD_DIM * LSEQ;
    const unsigned short* Qg = Qb + hbs * LSEQ * HEAD_DIM;

    const int sr = lane >> 3;
    const int scs = ((lane & 7) ^ sr) * 8;  // pre-swizzled source col (ushorts)

#define STAGE(buf, kt_) do {                                                     \
    load16_lds(Kg + (size_t)((kt_) * 64 + w * 8 + sr) * HEAD_DIM + scs,          \
               &Kls[buf][w * 8 * 64]);                                           \
    load16_lds(Vg + (size_t)(w * 8 + sr) * LSEQ + (kt_) * 64 + scs,              \
               &Vls[buf][w * 8 * 64]);                                           \
    } while (0)

#pragma unroll 1
    for (int pass = 0; pass < 2; ++pass) {
        const int qt = pass ? u : (15 - u);   // long tile first
        const int qr0 = qt * 128 + w * 16;    // wave's first q row

        bf16x8 qf[2];
        {
            const int qrow = qr0 + fr;
            qf[0] = *(const bf16x8*)&Qg[(size_t)qrow * HEAD_DIM + fq * 8];
            qf[1] = *(const bf16x8*)&Qg[(size_t)qrow * HEAD_DIM + 32 + fq * 8];
        }

        f32x4 acc_o[4] = {};
        float m_[4], ls[4];
#pragma unroll
        for (int r = 0; r < 4; ++r) { m_[r] = -INFINITY; ls[r] = 0.f; }

        const int nk = 2 * qt + 2;  // KV tiles covering this q-tile's causal span
        STAGE(0, 0);
        __syncthreads();

        int cur = 0;
        for (int kt = 0; kt < nk; ++kt) {
            if (kt < nk - 1) STAGE(cur ^ 1, kt + 1);

            if (kt * 64 <= qr0 + 15) {  // wave has unmasked keys in this tile
                // S = Q K^T (wave's 16 rows x 64 keys)
                f32x4 s[4] = {};
                __builtin_amdgcn_s_setprio(1);
#pragma unroll
                for (int nf = 0; nf < 4; ++nf) {
                    bf16x8 k0 = *(const bf16x8*)&Kls[cur][lidx(nf * 16 + fr, fq * 8)];
                    bf16x8 k1 = *(const bf16x8*)&Kls[cur][lidx(nf * 16 + fr, 32 + fq * 8)];
                    s[nf] = __builtin_amdgcn_mfma_f32_16x16x32_bf16(qf[0], k0, s[nf], 0, 0, 0);
                    s[nf] = __builtin_amdgcn_mfma_f32_16x16x32_bf16(qf[1], k1, s[nf], 0, 0, 0);
                }
                __builtin_amdgcn_s_setprio(0);

                if (kt * 64 + 63 > qr0) {  // diagonal band: mask kv > q
#pragma unroll
                    for (int nf = 0; nf < 4; ++nf)
#pragma unroll
                        for (int r = 0; r < 4; ++r)
                            if (kt * 64 + nf * 16 + fr > qr0 + fq * 4 + r)
                                s[nf][r] = -INFINITY;
                }

                // per-row tile max (16 lanes share a row)
                float v[4];
#pragma unroll
                for (int r = 0; r < 4; ++r) {
                    float t = fmaxf(fmaxf(s[0][r], s[1][r]), fmaxf(s[2][r], s[3][r]));
                    t = fmaxf(t, __shfl_xor(t, 1));
                    t = fmaxf(t, __shfl_xor(t, 2));
                    t = fmaxf(t, __shfl_xor(t, 4));
                    t = fmaxf(t, __shfl_xor(t, 8));
                    v[r] = t;
                }
                // defer-max: skip rescale unless some row's max grew past m+8
                const bool okl = (v[0] <= m_[0] + 8.f) && (v[1] <= m_[1] + 8.f) &&
                                 (v[2] <= m_[2] + 8.f) && (v[3] <= m_[3] + 8.f);
                if (!__all(okl)) {
#pragma unroll
                    for (int r = 0; r < 4; ++r) {
                        const float mn = fmaxf(m_[r], v[r]);
                        const float f = __expf(m_[r] - mn);  // -inf -> 0
                        m_[r] = mn;
                        ls[r] *= f;
                        acc_o[0][r] *= f; acc_o[1][r] *= f;
                        acc_o[2][r] *= f; acc_o[3][r] *= f;
                    }
                }

                float ps[4] = {0.f, 0.f, 0.f, 0.f};
#pragma unroll
                for (int nf = 0; nf < 4; ++nf)
#pragma unroll
                    for (int r = 0; r < 4; ++r) {
                        const float p = __expf(s[nf][r] - m_[r]);
                        s[nf][r] = p;
                        ps[r] += p;
                    }
#pragma unroll
                for (int r = 0; r < 4; ++r) {
                    float t = ps[r];
                    t += __shfl_xor(t, 1); t += __shfl_xor(t, 2);
                    t += __shfl_xor(t, 4); t += __shfl_xor(t, 8);
                    ls[r] += t;
                }

                // P -> LDS (bf16, swizzled) ; row = fq*4+r, col = nf*16+fr
#pragma unroll
                for (int nf = 0; nf < 4; ++nf)
#pragma unroll
                    for (int r = 0; r < 4; ++r)
                        Pls[w][lidx(fq * 4 + r, nf * 16 + fr)] = f2bf(s[nf][r]);

                // O += P @ V   (A-frag from Pls, B-frag from V^T tile)
                __builtin_amdgcn_s_setprio(1);
#pragma unroll
                for (int kf = 0; kf < 2; ++kf) {
                    bf16x8 pa = *(const bf16x8*)&Pls[w][lidx(fr, kf * 32 + fq * 8)];
#pragma unroll
                    for (int nf = 0; nf < 4; ++nf) {
                        bf16x8 vb = *(const bf16x8*)&Vls[cur][lidx(nf * 16 + fr, kf * 32 + fq * 8)];
                        acc_o[nf] = __builtin_amdgcn_mfma_f32_16x16x32_bf16(pa, vb, acc_o[nf], 0, 0, 0);
                    }
                }
                __builtin_amdgcn_s_setprio(0);
            }

            __syncthreads();  // drains STAGE vmcnt + protects both LDS buffers
            cur ^= 1;
        }

#pragma unroll
        for (int r = 0; r < 4; ++r) {
            const float inv = 1.f / ls[r];
            const int lq = qr0 + fq * 4 + r;
            const size_t rb = ((size_t)b * LSEQ + lq) * D_MODEL + h * HEAD_DIM;
#pragma unroll
            for (int nf = 0; nf < 4; ++nf)
                AO[rb + nf * 16 + fr] = f2bf(acc_o[nf][r] * inv);
        }
    }
#undef STAGE
}

// ---------------------------------------------------------------------------
// Output projection: out = AO @ Wo^T + bo, fp32 output.
// ---------------------------------------------------------------------------
__global__ __launch_bounds__(256) void oproj_mfma(
    const unsigned short* __restrict__ Ab, const unsigned short* __restrict__ Wob,
    const float* __restrict__ bo, float* __restrict__ out)
{
    __shared__ __align__(16) unsigned short Als[128 * 64];
    __shared__ __align__(16) unsigned short Bls[128 * 64];

    const int tid = threadIdx.x;
    const int w = tid >> 6, lane = tid & 63;
    const int wm = w >> 1, wn = w & 1;
    const int fr = lane & 15, fq = lane >> 4;
    const int i0 = blockIdx.x * 128, j0 = blockIdx.y * 128;

    const int sr = lane >> 3;
    const int scs = ((lane & 7) ^ (lane >> 3)) * 8;

    f32x4 acc[4][4] = {};

    for (int kt = 0; kt < D_MODEL / 64; ++kt) {
        const int k0 = kt * 64;
        __syncthreads();
#pragma unroll
        for (int t = 0; t < 4; ++t) {
            const int row = w * 32 + t * 8;
            load16_lds(&Ab[(size_t)(i0 + row + sr) * D_MODEL + k0 + scs], &Als[row * 64]);
            load16_lds(&Wob[(size_t)(j0 + row + sr) * D_MODEL + k0 + scs], &Bls[row * 64]);
        }
        __syncthreads();
#pragma unroll
        for (int kh = 0; kh < 2; ++kh) {
            bf16x8 af[4], bfr[4];
#pragma unroll
            for (int mf = 0; mf < 4; ++mf)
                af[mf] = *(const bf16x8*)&Als[lidx(wm * 64 + mf * 16 + fr, kh * 32 + fq * 8)];
#pragma unroll
            for (int nf = 0; nf < 4; ++nf)
                bfr[nf] = *(const bf16x8*)&Bls[lidx(wn * 64 + nf * 16 + fr, kh * 32 + fq * 8)];
#pragma unroll
            for (int mf = 0; mf < 4; ++mf)
#pragma unroll
                for (int nf = 0; nf < 4; ++nf)
                    acc[mf][nf] = __builtin_amdgcn_mfma_f32_16x16x32_bf16(
                        af[mf], bfr[nf], acc[mf][nf], 0, 0, 0);
        }
    }

    float bb[4];
#pragma unroll
    for (int nf = 0; nf < 4; ++nf) bb[nf] = bo[j0 + wn * 64 + nf * 16 + fr];
#pragma unroll
    for (int mf = 0; mf < 4; ++mf)
#pragma unroll
        for (int r = 0; r < 4; ++r) {
            const int i = i0 + wm * 64 + mf * 16 + fq * 4 + r;
#pragma unroll
            for (int nf = 0; nf < 4; ++nf)
                out[(size_t)i * D_MODEL + j0 + wn * 64 + nf * 16 + fr] =
                    acc[mf][nf][r] + bb[nf];
        }
}

// ---------------------------------------------------------------------------
extern "C" void kernel_launch(void* const* d_in, const int* in_sizes, int n_in,
                              void* d_out, int out_size, void* d_ws, size_t ws_size,
                              hipStream_t stream) {
    const float* x     = (const float*)d_in[0];
    // d_in[1]: causal mask (hardcoded in attn_mfma)
    const float* Wq    = (const float*)d_in[2];
    const float* bq    = (const float*)d_in[3];
    const float* Wk    = (const float*)d_in[4];
    const float* bk    = (const float*)d_in[5];
    const float* Wv    = (const float*)d_in[6];
    const float* bv    = (const float*)d_in[7];
    const float* Wo    = (const float*)d_in[8];
    const float* bo    = (const float*)d_in[9];
    const float* scale = (const float*)d_in[10];
    float* out = (float*)d_out;

    const size_t NE = (size_t)MROWS * D_MODEL;  // 8,388,608
    const size_t WE = (size_t)D_MODEL * D_MODEL;

    unsigned short* xb  = (unsigned short*)d_ws;  // reused as AO after qkv
    unsigned short* Qb  = xb + NE;
    unsigned short* Kb  = Qb + NE;
    unsigned short* Vt  = Kb + NE;
    unsigned short* wqb = Vt + NE;
    unsigned short* wkb = wqb + WE;
    unsigned short* wvb = wkb + WE;
    unsigned short* wob = wvb + WE;
    unsigned short* AO  = xb;   // x dead after qkv

    {
        const int total4 = (int)((NE + 4 * WE) / 4);  // 3,145,728
        cvt_all<<<total4 / 256, 256, 0, stream>>>(x, Wq, Wk, Wv, Wo,
                                                  xb, wqb, wkb, wvb, wob);
    }

    qkv_mfma<<<dim3(MROWS / 128, D_MODEL / 128, 3), 256, 0, stream>>>(
        xb, wqb, bq, wkb, bk, wvb, bv, scale, Qb, Kb, Vt);

    attn_mfma<<<512, 512, 0, stream>>>(Qb, Kb, Vt, AO);

    oproj_mfma<<<dim3(MROWS / 128, D_MODEL / 128), 256, 0, stream>>>(AO, wob, bo, out);
}

// Round 10
// 265.994 us; speedup vs baseline: 1.5301x; 1.1311x over previous
//
#include <hip/hip_runtime.h>
#include <cstdint>

#define D_MODEL 1024
#define NHEAD 16
#define HEAD_DIM 64
#define LSEQ 2048
#define BATCH 4
#define MROWS (BATCH * LSEQ)  // 8192

typedef __bf16 bf16x8 __attribute__((ext_vector_type(8)));
typedef float f32x4 __attribute__((ext_vector_type(4)));

// fp32 -> bf16 RNE
__device__ __forceinline__ unsigned short f2bf(float f) {
    unsigned b = __builtin_bit_cast(unsigned, f);
    b += 0x7FFFu + ((b >> 16) & 1u);
    return (unsigned short)(b >> 16);
}

// async global->LDS, 16B per lane; lds must be wave-uniform base (lane*16 added by HW)
__device__ __forceinline__ void load16_lds(const void* g, void* lds) {
    __builtin_amdgcn_global_load_lds(
        (const __attribute__((address_space(1))) void*)(uintptr_t)g,
        (__attribute__((address_space(3))) void*)(unsigned)(uintptr_t)lds,
        16, 0, 0);
}

// Swizzled ushort index into a [rows][64]-ushort (128B-row) LDS tile.
__device__ __forceinline__ int lidx(int row, int col /*ushort units*/) {
    return row * 64 + (col ^ ((row & 7) << 3));
}

// ---------------------------------------------------------------------------
// One fused cast launch: x (NE) + Wq,Wk,Wv,Wo (WE each), fp32 -> bf16.
// ---------------------------------------------------------------------------
__global__ __launch_bounds__(256) void cvt_all(
    const float* __restrict__ x, const float* __restrict__ wq,
    const float* __restrict__ wk, const float* __restrict__ wv,
    const float* __restrict__ wo,
    unsigned short* __restrict__ xb, unsigned short* __restrict__ wqb,
    unsigned short* __restrict__ wkb, unsigned short* __restrict__ wvb,
    unsigned short* __restrict__ wob)
{
    const int NE4 = (MROWS * D_MODEL) / 4;    // 2097152
    const int WE4 = (D_MODEL * D_MODEL) / 4;  // 262144 = 2^18
    int i = blockIdx.x * 256 + threadIdx.x;
    const float* src; unsigned short* dst; int off;
    if (i < NE4) { src = x; dst = xb; off = i; }
    else {
        int j = i - NE4;
        int seg = j >> 18;
        off = j & (WE4 - 1);
        src = (seg == 0) ? wq : (seg == 1) ? wk : (seg == 2) ? wv : wo;
        dst = (seg == 0) ? wqb : (seg == 1) ? wkb : (seg == 2) ? wvb : wob;
    }
    float4 v = ((const float4*)src)[off];
    ushort4 o;
    o.x = f2bf(v.x); o.y = f2bf(v.y); o.z = f2bf(v.z); o.w = f2bf(v.w);
    ((ushort4*)dst)[off] = o;
}

// ---------------------------------------------------------------------------
// QKV projection: C = X @ W^T + b, 128x128 tile, BK=64, 4 waves, MFMA 16x16x32.
// z = 0/1/2 -> Q/K/V.  Q,K: fused per-head L2norm * scale (Q also * hd^-0.5),
// layout [B,H,L,64].  V: written transposed [B,H,64,L].
// ---------------------------------------------------------------------------
__global__ __launch_bounds__(256) void qkv_mfma(
    const unsigned short* __restrict__ xb,
    const unsigned short* __restrict__ Wqb, const float* __restrict__ bq,
    const unsigned short* __restrict__ Wkb, const float* __restrict__ bk,
    const unsigned short* __restrict__ Wvb, const float* __restrict__ bv,
    const float* __restrict__ scale,
    unsigned short* __restrict__ Qo, unsigned short* __restrict__ Ko,
    unsigned short* __restrict__ Vt)
{
    __shared__ __align__(16) unsigned short Als[128 * 64];
    __shared__ __align__(16) unsigned short Bls[128 * 64];

    const int z = blockIdx.z;
    const unsigned short* Wb = (z == 0) ? Wqb : (z == 1) ? Wkb : Wvb;
    const float* bias        = (z == 0) ? bq  : (z == 1) ? bk  : bv;

    const int tid = threadIdx.x;
    const int w = tid >> 6, lane = tid & 63;
    const int wm = w >> 1, wn = w & 1;
    const int fr = lane & 15, fq = lane >> 4;
    const int i0 = blockIdx.x * 128, j0 = blockIdx.y * 128;

    const int sr = lane >> 3;
    const int scs = ((lane & 7) ^ (lane >> 3)) * 8;  // inverse-swizzled col (ushorts)

    f32x4 acc[4][4] = {};

    for (int kt = 0; kt < D_MODEL / 64; ++kt) {
        const int k0 = kt * 64;
        __syncthreads();
#pragma unroll
        for (int t = 0; t < 4; ++t) {
            const int row = w * 32 + t * 8;
            load16_lds(&xb[(size_t)(i0 + row + sr) * D_MODEL + k0 + scs], &Als[row * 64]);
            load16_lds(&Wb[(size_t)(j0 + row + sr) * D_MODEL + k0 + scs], &Bls[row * 64]);
        }
        __syncthreads();
#pragma unroll
        for (int kh = 0; kh < 2; ++kh) {
            bf16x8 af[4], bfr[4];
#pragma unroll
            for (int mf = 0; mf < 4; ++mf)
                af[mf] = *(const bf16x8*)&Als[lidx(wm * 64 + mf * 16 + fr, kh * 32 + fq * 8)];
#pragma unroll
            for (int nf = 0; nf < 4; ++nf)
                bfr[nf] = *(const bf16x8*)&Bls[lidx(wn * 64 + nf * 16 + fr, kh * 32 + fq * 8)];
#pragma unroll
            for (int mf = 0; mf < 4; ++mf)
#pragma unroll
                for (int nf = 0; nf < 4; ++nf)
                    acc[mf][nf] = __builtin_amdgcn_mfma_f32_16x16x32_bf16(
                        af[mf], bfr[nf], acc[mf][nf], 0, 0, 0);
        }
    }

    float bb[4];
#pragma unroll
    for (int nf = 0; nf < 4; ++nf) bb[nf] = bias[j0 + wn * 64 + nf * 16 + fr];
#pragma unroll
    for (int mf = 0; mf < 4; ++mf)
#pragma unroll
        for (int nf = 0; nf < 4; ++nf)
#pragma unroll
            for (int r = 0; r < 4; ++r) acc[mf][nf][r] += bb[nf];

    const int h = (j0 >> 6) + wn;  // head index of this wave's 64-col span

    if (z < 2) {
        const float sclr = scale[0] * ((z == 0) ? 0.125f : 1.0f);  // fold hd^-0.5 into Q
        unsigned short* out = (z == 0) ? Qo : Ko;
#pragma unroll
        for (int mf = 0; mf < 4; ++mf) {
#pragma unroll
            for (int r = 0; r < 4; ++r) {
                float ss = 0.f;
#pragma unroll
                for (int nf = 0; nf < 4; ++nf) ss += acc[mf][nf][r] * acc[mf][nf][r];
                ss += __shfl_xor(ss, 1); ss += __shfl_xor(ss, 2);
                ss += __shfl_xor(ss, 4); ss += __shfl_xor(ss, 8);
                const float inv = sclr / fmaxf(sqrtf(ss), 1e-12f);
                const int i = i0 + wm * 64 + mf * 16 + fq * 4 + r;
                const int bidx = i >> 11, lrow = i & (LSEQ - 1);
                const size_t rb = (((size_t)(bidx * NHEAD + h)) * LSEQ + lrow) * HEAD_DIM;
#pragma unroll
                for (int nf = 0; nf < 4; ++nf)
                    out[rb + nf * 16 + fr] = f2bf(acc[mf][nf][r] * inv);
            }
        }
    } else {
#pragma unroll
        for (int mf = 0; mf < 4; ++mf) {
            const int i = i0 + wm * 64 + mf * 16 + fq * 4;  // r=0 row; +r contiguous
            const int bidx = i >> 11, lrow = i & (LSEQ - 1);
#pragma unroll
            for (int nf = 0; nf < 4; ++nf) {
                const int d = nf * 16 + fr;
                const size_t a = (((size_t)(bidx * NHEAD + h)) * HEAD_DIM + d) * LSEQ + lrow;
                ushort4 pk;
                pk.x = f2bf(acc[mf][nf][0]); pk.y = f2bf(acc[mf][nf][1]);
                pk.z = f2bf(acc[mf][nf][2]); pk.w = f2bf(acc[mf][nf][3]);
                *(ushort4*)&Vt[a] = pk;
            }
        }
    }
}

// ---------------------------------------------------------------------------
// Causal flash attention, bf16 MFMA.  8 waves (512 thr), QBLK=128, triangular
// load balance (block = qt pair (15-u, u)), 512 uniform blocks.
// LAZY SOFTMAX: no per-tile cross-lane reductions.  Defer-max check uses
// per-lane max only (__all spans the full row); softmax denominator kept as
// per-lane partials, reduced ONCE per pass.  Full shfl reduce only inside the
// rare rescale branch (first tile / max growth > 8).
// ---------------------------------------------------------------------------
__global__ __launch_bounds__(512) void attn_mfma(
    const unsigned short* __restrict__ Qb, const unsigned short* __restrict__ Kb,
    const unsigned short* __restrict__ Vt, unsigned short* __restrict__ AO)
{
    __shared__ __align__(16) unsigned short Kls[2][64 * 64];
    __shared__ __align__(16) unsigned short Vls[2][64 * 64];
    __shared__ __align__(16) unsigned short Pls[8][16 * 64];

    const int pid = blockIdx.x;
    const int u = pid >> 6;           // 0..7  -> qt pair (15-u, u)
    const int hb = pid & 63;          // (b,h)
    const int h = hb & 15, b = hb >> 4;
    const int tid = threadIdx.x, w = tid >> 6, lane = tid & 63;
    const int fr = lane & 15, fq = lane >> 4;

    const size_t hbs = (size_t)(b * NHEAD + h);
    const unsigned short* Kg = Kb + hbs * LSEQ * HEAD_DIM;
    const unsigned short* Vg = Vt + hbs * HEAD_DIM * LSEQ;
    const unsigned short* Qg = Qb + hbs * LSEQ * HEAD_DIM;

    const int sr = lane >> 3;
    const int scs = ((lane & 7) ^ sr) * 8;  // pre-swizzled source col (ushorts)

#define STAGE(buf, kt_) do {                                                     \
    load16_lds(Kg + (size_t)((kt_) * 64 + w * 8 + sr) * HEAD_DIM + scs,          \
               &Kls[buf][w * 8 * 64]);                                           \
    load16_lds(Vg + (size_t)(w * 8 + sr) * LSEQ + (kt_) * 64 + scs,              \
               &Vls[buf][w * 8 * 64]);                                           \
    } while (0)

#pragma unroll 1
    for (int pass = 0; pass < 2; ++pass) {
        const int qt = pass ? u : (15 - u);   // long tile first
        const int qr0 = qt * 128 + w * 16;    // wave's first q row

        bf16x8 qf[2];
        {
            const int qrow = qr0 + fr;
            qf[0] = *(const bf16x8*)&Qg[(size_t)qrow * HEAD_DIM + fq * 8];
            qf[1] = *(const bf16x8*)&Qg[(size_t)qrow * HEAD_DIM + 32 + fq * 8];
        }

        f32x4 acc_o[4] = {};
        float m_[4], lsp[4];   // m_: row-uniform running max; lsp: PER-LANE partial sums
#pragma unroll
        for (int r = 0; r < 4; ++r) { m_[r] = -INFINITY; lsp[r] = 0.f; }

        const int nk = 2 * qt + 2;  // KV tiles covering this q-tile's causal span
        STAGE(0, 0);
        __syncthreads();

        int cur = 0;
        for (int kt = 0; kt < nk; ++kt) {
            if (kt < nk - 1) STAGE(cur ^ 1, kt + 1);

            if (kt * 64 <= qr0 + 15) {  // wave has unmasked keys in this tile
                // S = Q K^T (wave's 16 rows x 64 keys)
                f32x4 s[4] = {};
                __builtin_amdgcn_s_setprio(1);
#pragma unroll
                for (int nf = 0; nf < 4; ++nf) {
                    bf16x8 k0 = *(const bf16x8*)&Kls[cur][lidx(nf * 16 + fr, fq * 8)];
                    bf16x8 k1 = *(const bf16x8*)&Kls[cur][lidx(nf * 16 + fr, 32 + fq * 8)];
                    s[nf] = __builtin_amdgcn_mfma_f32_16x16x32_bf16(qf[0], k0, s[nf], 0, 0, 0);
                    s[nf] = __builtin_amdgcn_mfma_f32_16x16x32_bf16(qf[1], k1, s[nf], 0, 0, 0);
                }
                __builtin_amdgcn_s_setprio(0);

                if (kt * 64 + 63 > qr0) {  // diagonal band: mask kv > q
#pragma unroll
                    for (int nf = 0; nf < 4; ++nf)
#pragma unroll
                        for (int r = 0; r < 4; ++r)
                            if (kt * 64 + nf * 16 + fr > qr0 + fq * 4 + r)
                                s[nf][r] = -INFINITY;
                }

                // per-LANE max only (no shfl): __all below spans all 16 lanes
                // of each row, so the defer check is still row-complete.
                float v[4];
#pragma unroll
                for (int r = 0; r < 4; ++r)
                    v[r] = fmaxf(fmaxf(s[0][r], s[1][r]), fmaxf(s[2][r], s[3][r]));

                const bool okl = (v[0] <= m_[0] + 8.f) && (v[1] <= m_[1] + 8.f) &&
                                 (v[2] <= m_[2] + 8.f) && (v[3] <= m_[3] + 8.f);
                if (!__all(okl)) {
                    // rare path (first tile / max growth): full row reduce + rescale
#pragma unroll
                    for (int r = 0; r < 4; ++r) {
                        float t = v[r];
                        t = fmaxf(t, __shfl_xor(t, 1));
                        t = fmaxf(t, __shfl_xor(t, 2));
                        t = fmaxf(t, __shfl_xor(t, 4));
                        t = fmaxf(t, __shfl_xor(t, 8));
                        const float mn = fmaxf(m_[r], t);
                        const float f = __expf(m_[r] - mn);  // -inf -> 0
                        m_[r] = mn;
                        lsp[r] *= f;
                        acc_o[0][r] *= f; acc_o[1][r] *= f;
                        acc_o[2][r] *= f; acc_o[3][r] *= f;
                    }
                }

#pragma unroll
                for (int nf = 0; nf < 4; ++nf)
#pragma unroll
                    for (int r = 0; r < 4; ++r) {
                        const float p = __expf(s[nf][r] - m_[r]);
                        s[nf][r] = p;
                        lsp[r] += p;   // per-lane partial; reduced once per pass
                    }

                // P -> LDS (bf16, swizzled) ; row = fq*4+r, col = nf*16+fr
#pragma unroll
                for (int nf = 0; nf < 4; ++nf)
#pragma unroll
                    for (int r = 0; r < 4; ++r)
                        Pls[w][lidx(fq * 4 + r, nf * 16 + fr)] = f2bf(s[nf][r]);

                // O += P @ V   (A-frag from Pls, B-frag from V^T tile)
                __builtin_amdgcn_s_setprio(1);
#pragma unroll
                for (int kf = 0; kf < 2; ++kf) {
                    bf16x8 pa = *(const bf16x8*)&Pls[w][lidx(fr, kf * 32 + fq * 8)];
#pragma unroll
                    for (int nf = 0; nf < 4; ++nf) {
                        bf16x8 vb = *(const bf16x8*)&Vls[cur][lidx(nf * 16 + fr, kf * 32 + fq * 8)];
                        acc_o[nf] = __builtin_amdgcn_mfma_f32_16x16x32_bf16(pa, vb, acc_o[nf], 0, 0, 0);
                    }
                }
                __builtin_amdgcn_s_setprio(0);
            }

            __syncthreads();  // drains STAGE vmcnt + protects both LDS buffers
            cur ^= 1;
        }

        // once-per-pass denominator reduce (was per-tile before)
#pragma unroll
        for (int r = 0; r < 4; ++r) {
            float t = lsp[r];
            t += __shfl_xor(t, 1); t += __shfl_xor(t, 2);
            t += __shfl_xor(t, 4); t += __shfl_xor(t, 8);
            const float inv = 1.f / t;
            const int lq = qr0 + fq * 4 + r;
            const size_t rb = ((size_t)b * LSEQ + lq) * D_MODEL + h * HEAD_DIM;
#pragma unroll
            for (int nf = 0; nf < 4; ++nf)
                AO[rb + nf * 16 + fr] = f2bf(acc_o[nf][r] * inv);
        }
    }
#undef STAGE
}

// ---------------------------------------------------------------------------
// Output projection: out = AO @ Wo^T + bo, fp32 output.
// ---------------------------------------------------------------------------
__global__ __launch_bounds__(256) void oproj_mfma(
    const unsigned short* __restrict__ Ab, const unsigned short* __restrict__ Wob,
    const float* __restrict__ bo, float* __restrict__ out)
{
    __shared__ __align__(16) unsigned short Als[128 * 64];
    __shared__ __align__(16) unsigned short Bls[128 * 64];

    const int tid = threadIdx.x;
    const int w = tid >> 6, lane = tid & 63;
    const int wm = w >> 1, wn = w & 1;
    const int fr = lane & 15, fq = lane >> 4;
    const int i0 = blockIdx.x * 128, j0 = blockIdx.y * 128;

    const int sr = lane >> 3;
    const int scs = ((lane & 7) ^ (lane >> 3)) * 8;

    f32x4 acc[4][4] = {};

    for (int kt = 0; kt < D_MODEL / 64; ++kt) {
        const int k0 = kt * 64;
        __syncthreads();
#pragma unroll
        for (int t = 0; t < 4; ++t) {
            const int row = w * 32 + t * 8;
            load16_lds(&Ab[(size_t)(i0 + row + sr) * D_MODEL + k0 + scs], &Als[row * 64]);
            load16_lds(&Wob[(size_t)(j0 + row + sr) * D_MODEL + k0 + scs], &Bls[row * 64]);
        }
        __syncthreads();
#pragma unroll
        for (int kh = 0; kh < 2; ++kh) {
            bf16x8 af[4], bfr[4];
#pragma unroll
            for (int mf = 0; mf < 4; ++mf)
                af[mf] = *(const bf16x8*)&Als[lidx(wm * 64 + mf * 16 + fr, kh * 32 + fq * 8)];
#pragma unroll
            for (int nf = 0; nf < 4; ++nf)
                bfr[nf] = *(const bf16x8*)&Bls[lidx(wn * 64 + nf * 16 + fr, kh * 32 + fq * 8)];
#pragma unroll
            for (int mf = 0; mf < 4; ++mf)
#pragma unroll
                for (int nf = 0; nf < 4; ++nf)
                    acc[mf][nf] = __builtin_amdgcn_mfma_f32_16x16x32_bf16(
                        af[mf], bfr[nf], acc[mf][nf], 0, 0, 0);
        }
    }

    float bb[4];
#pragma unroll
    for (int nf = 0; nf < 4; ++nf) bb[nf] = bo[j0 + wn * 64 + nf * 16 + fr];
#pragma unroll
    for (int mf = 0; mf < 4; ++mf)
#pragma unroll
        for (int r = 0; r < 4; ++r) {
            const int i = i0 + wm * 64 + mf * 16 + fq * 4 + r;
#pragma unroll
            for (int nf = 0; nf < 4; ++nf)
                out[(size_t)i * D_MODEL + j0 + wn * 64 + nf * 16 + fr] =
                    acc[mf][nf][r] + bb[nf];
        }
}

// ---------------------------------------------------------------------------
extern "C" void kernel_launch(void* const* d_in, const int* in_sizes, int n_in,
                              void* d_out, int out_size, void* d_ws, size_t ws_size,
                              hipStream_t stream) {
    const float* x     = (const float*)d_in[0];
    // d_in[1]: causal mask (hardcoded in attn_mfma)
    const float* Wq    = (const float*)d_in[2];
    const float* bq    = (const float*)d_in[3];
    const float* Wk    = (const float*)d_in[4];
    const float* bk    = (const float*)d_in[5];
    const float* Wv    = (const float*)d_in[6];
    const float* bv    = (const float*)d_in[7];
    const float* Wo    = (const float*)d_in[8];
    const float* bo    = (const float*)d_in[9];
    const float* scale = (const float*)d_in[10];
    float* out = (float*)d_out;

    const size_t NE = (size_t)MROWS * D_MODEL;  // 8,388,608
    const size_t WE = (size_t)D_MODEL * D_MODEL;

    unsigned short* xb  = (unsigned short*)d_ws;  // reused as AO after qkv
    unsigned short* Qb  = xb + NE;
    unsigned short* Kb  = Qb + NE;
    unsigned short* Vt  = Kb + NE;
    unsigned short* wqb = Vt + NE;
    unsigned short* wkb = wqb + WE;
    unsigned short* wvb = wkb + WE;
    unsigned short* wob = wvb + WE;
    unsigned short* AO  = xb;   // x dead after qkv

    {
        const int total4 = (int)((NE + 4 * WE) / 4);  // 3,145,728
        cvt_all<<<total4 / 256, 256, 0, stream>>>(x, Wq, Wk, Wv, Wo,
                                                  xb, wqb, wkb, wvb, wob);
    }

    qkv_mfma<<<dim3(MROWS / 128, D_MODEL / 128, 3), 256, 0, stream>>>(
        xb, wqb, bq, wkb, bk, wvb, bv, scale, Qb, Kb, Vt);

    attn_mfma<<<512, 512, 0, stream>>>(Qb, Kb, Vt, AO);

    oproj_mfma<<<dim3(MROWS / 128, D_MODEL / 128), 256, 0, stream>>>(AO, wob, bo, out);
}